// Round 1
// baseline (1076.360 us; speedup 1.0000x reference)
//
#include <hip/hip_runtime.h>
#include <math.h>

static constexpr int B_ = 8, N_ = 1024, C_ = 768, H_ = 12, D_ = 64;

// ---------------------------------------------------------------------------
// Tiled fp32 GEMM: C[M,Ncols] = A[M,Kdim] @ W[Kdim,Ncols] (+ bias[Ncols])
// BM=BN=64, BK=32, 256 threads, 4x4 per thread.
// ---------------------------------------------------------------------------
__global__ __launch_bounds__(256)
void gemm_kernel(const float* __restrict__ A, const float* __restrict__ W,
                 const float* __restrict__ bias, float* __restrict__ Cout,
                 int M, int Ncols, int Kdim)
{
    __shared__ float As[32][68];   // [k][m], padded
    __shared__ float Bs[32][68];   // [k][n], padded

    const int tid = threadIdx.x;
    const int tx = tid & 15, ty = tid >> 4;
    const int row0 = blockIdx.x * 64;
    const int col0 = blockIdx.y * 64;

    float acc[4][4] = {{0.f, 0.f, 0.f, 0.f}};

    for (int k0 = 0; k0 < Kdim; k0 += 32) {
#pragma unroll
        for (int r = 0; r < 2; ++r) {
            int i = tid + 256 * r;
            int ar = i >> 3;              // row within tile, 0..63
            int ac = (i & 7) << 2;        // k within tile, 0..28 step 4
            const float4 a = *(const float4*)(A + (size_t)(row0 + ar) * Kdim + k0 + ac);
            As[ac + 0][ar] = a.x;
            As[ac + 1][ar] = a.y;
            As[ac + 2][ar] = a.z;
            As[ac + 3][ar] = a.w;
        }
#pragma unroll
        for (int r = 0; r < 2; ++r) {
            int i = tid + 256 * r;
            int kr = i >> 4;              // k within tile, 0..31
            int nc = (i & 15) << 2;       // n within tile, 0..60 step 4
            *(float4*)(&Bs[kr][nc]) =
                *(const float4*)(W + (size_t)(k0 + kr) * Ncols + col0 + nc);
        }
        __syncthreads();

#pragma unroll
        for (int kk = 0; kk < 32; ++kk) {
            const float4 a4 = *(const float4*)(&As[kk][ty * 4]);
            const float4 b4 = *(const float4*)(&Bs[kk][tx * 4]);
            const float av[4] = {a4.x, a4.y, a4.z, a4.w};
            const float bw[4] = {b4.x, b4.y, b4.z, b4.w};
#pragma unroll
            for (int i = 0; i < 4; ++i)
#pragma unroll
                for (int j = 0; j < 4; ++j)
                    acc[i][j] = fmaf(av[i], bw[j], acc[i][j]);
        }
        __syncthreads();
    }

#pragma unroll
    for (int i = 0; i < 4; ++i) {
        const int col = col0 + tx * 4;
        float4 v = make_float4(acc[i][0], acc[i][1], acc[i][2], acc[i][3]);
        if (bias) {
            const float4 bb = *(const float4*)(bias + col);
            v.x += bb.x; v.y += bb.y; v.z += bb.z; v.w += bb.w;
        }
        *(float4*)(Cout + (size_t)(row0 + ty * 4 + i) * Ncols + col) = v;
    }
}

// ---------------------------------------------------------------------------
// Depthwise causal conv over the BATCH axis (the module's quirk):
//   out[b,n,c] = bias[c] + w[c,0]*in[b-2,n,c] + w[c,1]*in[b-1,n,c] + w[c,2]*in[b,n,c]
// in: [B,N,C]; w: [C,3]; out layout [B,H,N,D] for attention.
// ---------------------------------------------------------------------------
__global__ __launch_bounds__(256)
void dwconv_kernel(const float* __restrict__ lin, const float* __restrict__ w,
                   const float* __restrict__ bias, float* __restrict__ out)
{
    const int i = blockIdx.x * 256 + threadIdx.x;     // float4 index
    const int c4 = i % (C_ / 4);
    const int n  = (i / (C_ / 4)) % N_;
    const int b  = i / ((C_ / 4) * N_);
    const int c  = c4 * 4;

    float4 x0 = make_float4(0.f, 0.f, 0.f, 0.f);
    float4 x1 = x0;
    if (b >= 2) x0 = *(const float4*)(lin + ((size_t)(b - 2) * N_ + n) * C_ + c);
    if (b >= 1) x1 = *(const float4*)(lin + ((size_t)(b - 1) * N_ + n) * C_ + c);
    const float4 x2 = *(const float4*)(lin + ((size_t)b * N_ + n) * C_ + c);
    const float4 bb = *(const float4*)(bias + c);

    float4 y;
    y.x = fmaf(w[(c + 0) * 3 + 0], x0.x, fmaf(w[(c + 0) * 3 + 1], x1.x, fmaf(w[(c + 0) * 3 + 2], x2.x, bb.x)));
    y.y = fmaf(w[(c + 1) * 3 + 0], x0.y, fmaf(w[(c + 1) * 3 + 1], x1.y, fmaf(w[(c + 1) * 3 + 2], x2.y, bb.y)));
    y.z = fmaf(w[(c + 2) * 3 + 0], x0.z, fmaf(w[(c + 2) * 3 + 1], x1.z, fmaf(w[(c + 2) * 3 + 2], x2.z, bb.z)));
    y.w = fmaf(w[(c + 3) * 3 + 0], x0.w, fmaf(w[(c + 3) * 3 + 1], x1.w, fmaf(w[(c + 3) * 3 + 2], x2.w, bb.w)));

    const int h = c / D_, d = c % D_;
    *(float4*)(out + (((size_t)b * H_ + h) * N_ + n) * D_ + d) = y;
}

// ---------------------------------------------------------------------------
// Flash-style attention, fp32. Q/K/V layout [B*H, N, D]. One block handles
// 64 q-rows of one (b,h). Online softmax, 16-lane shfl row reductions.
// Out written as [B, N, H*D] for the final projection GEMM.
// LDS: Qs + Ks + Vs = 51.2 KB (P reuses Ks after a barrier).
// ---------------------------------------------------------------------------
__global__ __launch_bounds__(256)
void attn_kernel(const float* __restrict__ Qg, const float* __restrict__ Kg,
                 const float* __restrict__ Vg, float* __restrict__ Og)
{
    __shared__ float Qs[64][68];
    __shared__ float Ks[64][68];   // reused to hold P after S is consumed
    __shared__ float Vs[64][64];

    const int tid = threadIdx.x;
    const int tx = tid & 15, ty = tid >> 4;
    const int bh = blockIdx.y;
    const int b = bh / H_, h = bh % H_;
    const int q0 = blockIdx.x * 64;

    const float* Qp = Qg + (size_t)bh * N_ * D_;
    const float* Kp = Kg + (size_t)bh * N_ * D_;
    const float* Vp = Vg + (size_t)bh * N_ * D_;

    // load Q tile [64][64]
#pragma unroll
    for (int r = 0; r < 4; ++r) {
        int i = tid + 256 * r;
        int rr = i >> 4;
        int cc = (i & 15) * 4;
        *(float4*)(&Qs[rr][cc]) = *(const float4*)(Qp + (size_t)(q0 + rr) * D_ + cc);
    }

    float o[4][4] = {{0.f, 0.f, 0.f, 0.f}};
    float mrow[4], lrow[4];
#pragma unroll
    for (int i = 0; i < 4; ++i) { mrow[i] = -1e30f; lrow[i] = 0.f; }

    for (int kt = 0; kt < N_ / 64; ++kt) {
        __syncthreads();   // prev tile fully consumed (also covers Q load)
#pragma unroll
        for (int r = 0; r < 4; ++r) {
            int i = tid + 256 * r;
            int rr = i >> 4;
            int cc = (i & 15) * 4;
            *(float4*)(&Ks[rr][cc]) = *(const float4*)(Kp + (size_t)(kt * 64 + rr) * D_ + cc);
            *(float4*)(&Vs[rr][cc]) = *(const float4*)(Vp + (size_t)(kt * 64 + rr) * D_ + cc);
        }
        __syncthreads();

        // S = Q K^T for this tile: thread owns rows 4ty.., cols 4tx..
        float s[4][4] = {{0.f, 0.f, 0.f, 0.f}};
#pragma unroll
        for (int d4 = 0; d4 < 16; ++d4) {
            float qv[4][4], kv[4][4];
#pragma unroll
            for (int i = 0; i < 4; ++i) {
                const float4 t = *(const float4*)(&Qs[ty * 4 + i][d4 * 4]);
                qv[i][0] = t.x; qv[i][1] = t.y; qv[i][2] = t.z; qv[i][3] = t.w;
            }
#pragma unroll
            for (int j = 0; j < 4; ++j) {
                const float4 t = *(const float4*)(&Ks[tx * 4 + j][d4 * 4]);
                kv[j][0] = t.x; kv[j][1] = t.y; kv[j][2] = t.z; kv[j][3] = t.w;
            }
#pragma unroll
            for (int i = 0; i < 4; ++i)
#pragma unroll
                for (int j = 0; j < 4; ++j)
#pragma unroll
                    for (int d = 0; d < 4; ++d)
                        s[i][j] = fmaf(qv[i][d], kv[j][d], s[i][j]);
        }

        __syncthreads();   // everyone done reading Ks → safe to overwrite with P

        // online softmax update; P written into Ks (same-wave rows only)
#pragma unroll
        for (int i = 0; i < 4; ++i) {
            float tm = -1e30f;
#pragma unroll
            for (int j = 0; j < 4; ++j) { s[i][j] *= 0.125f; tm = fmaxf(tm, s[i][j]); }
#pragma unroll
            for (int mk = 1; mk < 16; mk <<= 1) tm = fmaxf(tm, __shfl_xor(tm, mk));
            const float mnew = fmaxf(mrow[i], tm);
            const float f = __expf(mrow[i] - mnew);
            float rs = 0.f;
#pragma unroll
            for (int j = 0; j < 4; ++j) {
                const float p = __expf(s[i][j] - mnew);
                s[i][j] = p; rs += p;
            }
#pragma unroll
            for (int mk = 1; mk < 16; mk <<= 1) rs += __shfl_xor(rs, mk);
            lrow[i] = lrow[i] * f + rs;
            mrow[i] = mnew;
#pragma unroll
            for (int j = 0; j < 4; ++j) o[i][j] *= f;
            *(float4*)(&Ks[ty * 4 + i][tx * 4]) = make_float4(s[i][0], s[i][1], s[i][2], s[i][3]);
        }
        // PV: rows of P read back only by the wave that wrote them (same ty),
        // LDS ops are in-order within a wave → no barrier needed here.
#pragma unroll
        for (int j4 = 0; j4 < 16; ++j4) {
            float pv[4][4], vv[4][4];
#pragma unroll
            for (int i = 0; i < 4; ++i) {
                const float4 t = *(const float4*)(&Ks[ty * 4 + i][j4 * 4]);
                pv[i][0] = t.x; pv[i][1] = t.y; pv[i][2] = t.z; pv[i][3] = t.w;
            }
#pragma unroll
            for (int jj = 0; jj < 4; ++jj) {
                const float4 t = *(const float4*)(&Vs[j4 * 4 + jj][tx * 4]);
                vv[jj][0] = t.x; vv[jj][1] = t.y; vv[jj][2] = t.z; vv[jj][3] = t.w;
            }
#pragma unroll
            for (int i = 0; i < 4; ++i)
#pragma unroll
                for (int d = 0; d < 4; ++d)
#pragma unroll
                    for (int jj = 0; jj < 4; ++jj)
                        o[i][d] = fmaf(pv[i][jj], vv[jj][d], o[i][d]);
        }
    }

    // epilogue: normalize and write [B,N,C] with c = h*64 + d
#pragma unroll
    for (int i = 0; i < 4; ++i) {
        const float inv = 1.0f / lrow[i];
        const float4 v = make_float4(o[i][0] * inv, o[i][1] * inv, o[i][2] * inv, o[i][3] * inv);
        *(float4*)(Og + ((size_t)b * N_ + q0 + ty * 4 + i) * C_ + h * D_ + tx * 4) = v;
    }
}

// ---------------------------------------------------------------------------
extern "C" void kernel_launch(void* const* d_in, const int* in_sizes, int n_in,
                              void* d_out, int out_size, void* d_ws, size_t ws_size,
                              hipStream_t stream)
{
    (void)in_sizes; (void)n_in; (void)out_size; (void)ws_size;
    const float* x    = (const float*)d_in[0];
    const float* wq   = (const float*)d_in[1];
    const float* wk   = (const float*)d_in[2];
    const float* wv   = (const float*)d_in[3];
    const float* bv   = (const float*)d_in[4];
    const float* cq_w = (const float*)d_in[5];
    const float* cq_b = (const float*)d_in[6];
    const float* ck_w = (const float*)d_in[7];
    const float* ck_b = (const float*)d_in[8];
    const float* cv_w = (const float*)d_in[9];
    const float* cv_b = (const float*)d_in[10];
    const float* wo   = (const float*)d_in[11];
    const float* bo   = (const float*)d_in[12];
    float* out = (float*)d_out;

    float* ws = (float*)d_ws;
    const size_t T = (size_t)B_ * N_ * C_;   // 6,291,456 elems per tensor
    float* q_lin = ws;
    float* k_lin = ws + T;
    float* v_lin = ws + 2 * T;
    float* qc    = ws + 3 * T;
    float* kc    = ws + 4 * T;
    float* vc    = ws + 5 * T;
    float* attn_out = q_lin;                 // q_lin dead after conv → reuse

    const dim3 gg(128, 12), bb(256);
    const int M = B_ * N_;

    gemm_kernel<<<gg, bb, 0, stream>>>(x, wq, nullptr, q_lin, M, C_, C_);
    gemm_kernel<<<gg, bb, 0, stream>>>(x, wk, nullptr, k_lin, M, C_, C_);
    gemm_kernel<<<gg, bb, 0, stream>>>(x, wv, bv,      v_lin, M, C_, C_);

    const int convBlocks = (B_ * N_ * (C_ / 4)) / 256;   // 6144
    dwconv_kernel<<<convBlocks, 256, 0, stream>>>(q_lin, cq_w, cq_b, qc);
    dwconv_kernel<<<convBlocks, 256, 0, stream>>>(k_lin, ck_w, ck_b, kc);
    dwconv_kernel<<<convBlocks, 256, 0, stream>>>(v_lin, cv_w, cv_b, vc);

    attn_kernel<<<dim3(N_ / 64, B_ * H_), 256, 0, stream>>>(qc, kc, vc, attn_out);

    gemm_kernel<<<gg, bb, 0, stream>>>(attn_out, wo, bo, out, M, C_, C_);
}

// Round 2
// 406.794 us; speedup vs baseline: 2.6460x; 2.6460x over previous
//
#include <hip/hip_runtime.h>
#include <math.h>

static constexpr int B_ = 8, N_ = 1024, C_ = 768, H_ = 12, D_ = 64;

typedef __bf16 bf16_t;
typedef bf16_t bf16x8 __attribute__((ext_vector_type(8)));
typedef float f32x4 __attribute__((ext_vector_type(4)));

#define MFMA16(a, b, c) __builtin_amdgcn_mfma_f32_16x16x32_bf16((a), (b), (c), 0, 0, 0)

__device__ __forceinline__ unsigned short f2bf(float f) {
    unsigned u = __builtin_bit_cast(unsigned, f);
    u += 0x7FFFu + ((u >> 16) & 1u);          // round-nearest-even
    return (unsigned short)(u >> 16);
}

__device__ __forceinline__ void gload16(void* lds, const void* g) {
    __builtin_amdgcn_global_load_lds(
        (const __attribute__((address_space(1))) unsigned int*)g,
        (__attribute__((address_space(3))) unsigned int*)lds, 16, 0, 0);
}

// swizzled byte offset for [row][64 bf16] tiles (128B rows), 16B slots
__device__ __forceinline__ int swz(int row, int kslot) {
    return row * 128 + (((kslot ^ row) & 7) << 4);
}

// ---------------------------------------------------------------------------
// fp32 → bf16 cast, 8 elems/thread
// ---------------------------------------------------------------------------
__global__ __launch_bounds__(256)
void castx_kernel(const float* __restrict__ in, unsigned short* __restrict__ out)
{
    const int i = blockIdx.x * 256 + threadIdx.x;
    const float4 a = ((const float4*)in)[2 * i];
    const float4 b = ((const float4*)in)[2 * i + 1];
    uint4 o;
    o.x = f2bf(a.x) | ((unsigned)f2bf(a.y) << 16);
    o.y = f2bf(a.z) | ((unsigned)f2bf(a.w) << 16);
    o.z = f2bf(b.x) | ((unsigned)f2bf(b.y) << 16);
    o.w = f2bf(b.z) | ((unsigned)f2bf(b.w) << 16);
    ((uint4*)out)[i] = o;
}

// ---------------------------------------------------------------------------
// transpose+cast weight [768,768] fp32 -> bf16 [N][K]
// ---------------------------------------------------------------------------
__global__ __launch_bounds__(256)
void castwT_kernel(const float* __restrict__ w, unsigned short* __restrict__ wT)
{
    __shared__ float T[64][65];
    const int t = threadIdx.x;
    const int k0 = blockIdx.x * 64, n0 = blockIdx.y * 64;
    const int r = t >> 2, c0 = (t & 3) * 16;
#pragma unroll
    for (int j4 = 0; j4 < 4; ++j4) {
        const float4 v = *(const float4*)(w + (size_t)(k0 + r) * 768 + n0 + c0 + j4 * 4);
        T[r][c0 + j4 * 4 + 0] = v.x; T[r][c0 + j4 * 4 + 1] = v.y;
        T[r][c0 + j4 * 4 + 2] = v.z; T[r][c0 + j4 * 4 + 3] = v.w;
    }
    __syncthreads();
    const int nn = t >> 2;
    unsigned short o[16];
#pragma unroll
    for (int j = 0; j < 16; ++j) o[j] = f2bf(T[c0 + j][nn]);
    uint4* dst = (uint4*)(wT + (size_t)(n0 + nn) * 768 + k0 + c0);
    dst[0] = *(uint4*)(o); dst[1] = *(uint4*)(o + 8);
}

// ---------------------------------------------------------------------------
// bf16 MFMA GEMM: C[M,N] f32 = A[M,K]bf16 @ BT[N,K]bf16^T (+bias)
// BM=64, BN=128, BK=64; 4 waves (2x2), wave = 32x64 out; 16x16x32 MFMA
// ---------------------------------------------------------------------------
__global__ __launch_bounds__(256)
void gemm_bf16(const unsigned short* __restrict__ A, const unsigned short* __restrict__ BT,
               const float* __restrict__ bias, float* __restrict__ Cmat,
               int M, int Ncols, int Kdim)
{
    __shared__ char As[64 * 128];     // [64 rows][64 bf16] swizzled
    __shared__ char Bs[128 * 128];    // [128 rows][64 bf16] swizzled

    const int tid = threadIdx.x, lane = tid & 63, w = tid >> 6;
    const int wr = w >> 1, wc = w & 1;
    const int slot = lane & 7, rsub = lane >> 3;
    const int row0 = blockIdx.x * 64, col0 = blockIdx.y * 128;

    f32x4 acc[2][4] = {};

    for (int k0 = 0; k0 < Kdim; k0 += 64) {
#pragma unroll
        for (int c = 0; c < 2; ++c) {
            const int chunk = c * 4 + w;
            const int r = chunk * 8 + rsub;
            gload16(As + chunk * 1024, A + (size_t)(row0 + r) * Kdim + k0 + 8 * (slot ^ (r & 7)));
        }
#pragma unroll
        for (int c = 0; c < 4; ++c) {
            const int chunk = c * 4 + w;
            const int r = chunk * 8 + rsub;
            gload16(Bs + chunk * 1024, BT + (size_t)(col0 + r) * Kdim + k0 + 8 * (slot ^ (r & 7)));
        }
        __syncthreads();

#pragma unroll
        for (int kk = 0; kk < 2; ++kk) {
            const int kslot = kk * 4 + (lane >> 4);
            bf16x8 af[2], bf[4];
#pragma unroll
            for (int mi = 0; mi < 2; ++mi)
                af[mi] = *(const bf16x8*)(As + swz(wr * 32 + mi * 16 + (lane & 15), kslot));
#pragma unroll
            for (int ni = 0; ni < 4; ++ni)
                bf[ni] = *(const bf16x8*)(Bs + swz(wc * 64 + ni * 16 + (lane & 15), kslot));
#pragma unroll
            for (int mi = 0; mi < 2; ++mi)
#pragma unroll
                for (int ni = 0; ni < 4; ++ni)
                    acc[mi][ni] = MFMA16(af[mi], bf[ni], acc[mi][ni]);
        }
        __syncthreads();
    }

#pragma unroll
    for (int mi = 0; mi < 2; ++mi) {
        const int row = row0 + wr * 32 + mi * 16 + ((lane >> 4) << 2);
#pragma unroll
        for (int ni = 0; ni < 4; ++ni) {
            const int col = col0 + wc * 64 + ni * 16 + (lane & 15);
            const float bv_ = bias ? bias[col] : 0.f;
#pragma unroll
            for (int r = 0; r < 4; ++r)
                Cmat[(size_t)(row + r) * Ncols + col] = acc[mi][ni][r] + bv_;
        }
    }
}

// ---------------------------------------------------------------------------
// depthwise causal conv over BATCH axis, fp32 in [B,N,C] -> bf16 out [B,H,N,D]
// ---------------------------------------------------------------------------
__global__ __launch_bounds__(256)
void dwconv_bf16(const float* __restrict__ lin, const float* __restrict__ w,
                 const float* __restrict__ bias, unsigned short* __restrict__ out)
{
    const int i = blockIdx.x * 256 + threadIdx.x;
    const int c4 = i % (C_ / 4);
    const int n  = (i / (C_ / 4)) % N_;
    const int b  = i / ((C_ / 4) * N_);
    const int c  = c4 * 4;

    float4 x0 = make_float4(0.f, 0.f, 0.f, 0.f);
    float4 x1 = x0;
    if (b >= 2) x0 = *(const float4*)(lin + ((size_t)(b - 2) * N_ + n) * C_ + c);
    if (b >= 1) x1 = *(const float4*)(lin + ((size_t)(b - 1) * N_ + n) * C_ + c);
    const float4 x2 = *(const float4*)(lin + ((size_t)b * N_ + n) * C_ + c);
    const float4 bb = *(const float4*)(bias + c);

    float4 y;
    y.x = fmaf(w[(c + 0) * 3 + 0], x0.x, fmaf(w[(c + 0) * 3 + 1], x1.x, fmaf(w[(c + 0) * 3 + 2], x2.x, bb.x)));
    y.y = fmaf(w[(c + 1) * 3 + 0], x0.y, fmaf(w[(c + 1) * 3 + 1], x1.y, fmaf(w[(c + 1) * 3 + 2], x2.y, bb.y)));
    y.z = fmaf(w[(c + 2) * 3 + 0], x0.z, fmaf(w[(c + 2) * 3 + 1], x1.z, fmaf(w[(c + 2) * 3 + 2], x2.z, bb.z)));
    y.w = fmaf(w[(c + 3) * 3 + 0], x0.w, fmaf(w[(c + 3) * 3 + 1], x1.w, fmaf(w[(c + 3) * 3 + 2], x2.w, bb.w)));

    const int h = c / D_, d = c % D_;
    ushort4 o;
    o.x = f2bf(y.x); o.y = f2bf(y.y); o.z = f2bf(y.z); o.w = f2bf(y.w);
    *(ushort4*)(out + (((size_t)b * H_ + h) * N_ + n) * D_ + d) = o;
}

// ---------------------------------------------------------------------------
// bf16 transpose [BH,N,64] -> [BH,64,N], 64x64 tiles
// ---------------------------------------------------------------------------
__global__ __launch_bounds__(256)
void transpose64(const unsigned short* __restrict__ in, unsigned short* __restrict__ out)
{
    __shared__ unsigned short T[64][67];
    const int t = threadIdx.x;
    const int bh = blockIdx.y, n0 = blockIdx.x * 64;
    const int r = t >> 2, c0 = (t & 3) * 16;

    const uint4* src = (const uint4*)(in + ((size_t)bh * N_ + n0 + r) * 64 + c0);
    unsigned short tmp[16];
    *(uint4*)(tmp) = src[0];
    *(uint4*)(tmp + 8) = src[1];
#pragma unroll
    for (int j = 0; j < 16; ++j) T[r][c0 + j] = tmp[j];
    __syncthreads();

    const int d = t >> 2;
    unsigned short o[16];
#pragma unroll
    for (int j = 0; j < 16; ++j) o[j] = T[c0 + j][d];
    uint4* dst = (uint4*)(out + ((size_t)bh * 64 + d) * N_ + n0 + c0);
    dst[0] = *(uint4*)(o); dst[1] = *(uint4*)(o + 8);
}

// ---------------------------------------------------------------------------
// MFMA flash attention. Q,K: [BH,N,64] bf16; Vt: [BH,64,N] bf16; O: [B,N,C] f32
// Block: 128 q-rows of one bh; 4 waves x 32 rows; KV tiles 64, double-buffered.
// ---------------------------------------------------------------------------
__global__ __launch_bounds__(256)
void attn_mfma(const unsigned short* __restrict__ Qg, const unsigned short* __restrict__ Kg,
               const unsigned short* __restrict__ Vtg, float* __restrict__ Og)
{
    __shared__ char Pb[16384];      // Q staging, then per-wave P tiles
    __shared__ char Kb[2][8192];
    __shared__ char Vb[2][8192];

    const int tid = threadIdx.x, lane = tid & 63, w = tid >> 6;
    const int slot = lane & 7, rsub = lane >> 3;
    const int bh = blockIdx.y, b = bh / H_, h = bh % H_;
    const int q0 = blockIdx.x * 128;

    const unsigned short* Qp = Qg + (size_t)bh * N_ * 64;
    const unsigned short* Kp = Kg + (size_t)bh * N_ * 64;
    const unsigned short* Vp = Vtg + (size_t)bh * 64 * N_;

    // stage Q (16KB) into Pb
#pragma unroll
    for (int c = 0; c < 4; ++c) {
        const int chunk = c * 4 + w;
        const int r = chunk * 8 + rsub;
        gload16(Pb + chunk * 1024, Qp + (size_t)(q0 + r) * 64 + 8 * (slot ^ (r & 7)));
    }
    // stage K,V tile 0 into buf 0
#pragma unroll
    for (int c = 0; c < 2; ++c) {
        const int chunk = c * 4 + w;
        const int r = chunk * 8 + rsub;
        gload16(Kb[0] + chunk * 1024, Kp + (size_t)r * 64 + 8 * (slot ^ (r & 7)));
        gload16(Vb[0] + chunk * 1024, Vp + (size_t)r * N_ + 8 * (slot ^ (r & 7)));
    }
    __syncthreads();

    // Q fragments (held whole kernel)
    bf16x8 qf[2][2];
#pragma unroll
    for (int mi = 0; mi < 2; ++mi)
#pragma unroll
        for (int kk = 0; kk < 2; ++kk)
            qf[mi][kk] = *(const bf16x8*)(Pb + swz(w * 32 + mi * 16 + (lane & 15), kk * 4 + (lane >> 4)));

    f32x4 o[2][4] = {};
    float mrow[2][4], lrow[2][4];
#pragma unroll
    for (int mi = 0; mi < 2; ++mi)
#pragma unroll
        for (int r = 0; r < 4; ++r) { mrow[mi][r] = -1e30f; lrow[mi][r] = 0.f; }

    int buf = 0;
    for (int kt = 0; kt < N_ / 64; ++kt) {
        if (kt < N_ / 64 - 1) {
            const int nb = buf ^ 1;
#pragma unroll
            for (int c = 0; c < 2; ++c) {
                const int chunk = c * 4 + w;
                const int r = chunk * 8 + rsub;
                gload16(Kb[nb] + chunk * 1024, Kp + (size_t)((kt + 1) * 64 + r) * 64 + 8 * (slot ^ (r & 7)));
                gload16(Vb[nb] + chunk * 1024, Vp + (size_t)r * N_ + (kt + 1) * 64 + 8 * (slot ^ (r & 7)));
            }
        }

        // ---- S = Q K^T (16 MFMA) ----
        f32x4 s[2][4] = {};
#pragma unroll
        for (int kk = 0; kk < 2; ++kk) {
            const int kslot = kk * 4 + (lane >> 4);
            bf16x8 kf[4];
#pragma unroll
            for (int ni = 0; ni < 4; ++ni)
                kf[ni] = *(const bf16x8*)(Kb[buf] + swz(ni * 16 + (lane & 15), kslot));
#pragma unroll
            for (int mi = 0; mi < 2; ++mi)
#pragma unroll
                for (int ni = 0; ni < 4; ++ni)
                    s[mi][ni] = MFMA16(qf[mi][kk], kf[ni], s[mi][ni]);
        }

        // ---- online softmax + P write (wave-private region of Pb) ----
#pragma unroll
        for (int mi = 0; mi < 2; ++mi) {
            float pv[4][4];     // [r][ni]
#pragma unroll
            for (int r = 0; r < 4; ++r) {
                const float a0 = s[mi][0][r] * 0.125f, a1 = s[mi][1][r] * 0.125f;
                const float a2 = s[mi][2][r] * 0.125f, a3 = s[mi][3][r] * 0.125f;
                pv[r][0] = a0; pv[r][1] = a1; pv[r][2] = a2; pv[r][3] = a3;
                float m0 = fmaxf(fmaxf(a0, a1), fmaxf(a2, a3));
#pragma unroll
                for (int mk = 1; mk < 16; mk <<= 1) m0 = fmaxf(m0, __shfl_xor(m0, mk));
                const float mold = mrow[mi][r];
                const float mnew = fmaxf(mold, m0);
                const float f = __expf(mold - mnew);
                mrow[mi][r] = mnew;
                float ssum = 0.f;
#pragma unroll
                for (int ni = 0; ni < 4; ++ni) {
                    const float e = __expf(pv[r][ni] - mnew);
                    pv[r][ni] = e; ssum += e;
                }
#pragma unroll
                for (int mk = 1; mk < 16; mk <<= 1) ssum += __shfl_xor(ssum, mk);
                lrow[mi][r] = lrow[mi][r] * f + ssum;
#pragma unroll
                for (int nd = 0; nd < 4; ++nd) o[mi][nd][r] *= f;
            }
            const int prow_base = w * 32 + mi * 16 + ((lane >> 4) << 2);
#pragma unroll
            for (int r = 0; r < 4; ++r) {
                const int m = prow_base + r;
                const int rowoff = m * 128, sw = (m & 7) << 4;
#pragma unroll
                for (int ni = 0; ni < 4; ++ni) {
                    const int col = ni * 16 + (lane & 15);
                    *(unsigned short*)(Pb + rowoff + ((col * 2) ^ sw)) = f2bf(pv[r][ni]);
                }
            }
        }

        // ---- O += P V (16 MFMA) ----
#pragma unroll
        for (int kk = 0; kk < 2; ++kk) {
            const int kslot = kk * 4 + (lane >> 4);
            bf16x8 pa[2], vf[4];
#pragma unroll
            for (int mi = 0; mi < 2; ++mi)
                pa[mi] = *(const bf16x8*)(Pb + swz(w * 32 + mi * 16 + (lane & 15), kslot));
#pragma unroll
            for (int nd = 0; nd < 4; ++nd)
                vf[nd] = *(const bf16x8*)(Vb[buf] + swz(nd * 16 + (lane & 15), kslot));
#pragma unroll
            for (int mi = 0; mi < 2; ++mi)
#pragma unroll
                for (int nd = 0; nd < 4; ++nd)
                    o[mi][nd] = MFMA16(pa[mi], vf[nd], o[mi][nd]);
        }

        __syncthreads();
        buf ^= 1;
    }

    // epilogue: normalize, write [B,N,C] fp32
#pragma unroll
    for (int mi = 0; mi < 2; ++mi)
#pragma unroll
        for (int r = 0; r < 4; ++r) {
            const float inv = 1.0f / lrow[mi][r];
            const int qrow = q0 + w * 32 + mi * 16 + ((lane >> 4) << 2) + r;
            float* orow = Og + ((size_t)b * N_ + qrow) * C_ + h * D_ + (lane & 15);
#pragma unroll
            for (int nd = 0; nd < 4; ++nd) orow[nd * 16] = o[mi][nd][r] * inv;
        }
}

// ---------------------------------------------------------------------------
// fp32 GEMM (final projection only): C = A @ W + bias
// ---------------------------------------------------------------------------
__global__ __launch_bounds__(256)
void gemm_kernel(const float* __restrict__ A, const float* __restrict__ W,
                 const float* __restrict__ bias, float* __restrict__ Cout,
                 int M, int Ncols, int Kdim)
{
    __shared__ float As[32][68];
    __shared__ float Bs[32][68];

    const int tid = threadIdx.x;
    const int tx = tid & 15, ty = tid >> 4;
    const int row0 = blockIdx.x * 64;
    const int col0 = blockIdx.y * 64;

    float acc[4][4] = {{0.f, 0.f, 0.f, 0.f}};

    for (int k0 = 0; k0 < Kdim; k0 += 32) {
#pragma unroll
        for (int r = 0; r < 2; ++r) {
            int i = tid + 256 * r;
            int ar = i >> 3;
            int ac = (i & 7) << 2;
            const float4 a = *(const float4*)(A + (size_t)(row0 + ar) * Kdim + k0 + ac);
            As[ac + 0][ar] = a.x; As[ac + 1][ar] = a.y;
            As[ac + 2][ar] = a.z; As[ac + 3][ar] = a.w;
        }
#pragma unroll
        for (int r = 0; r < 2; ++r) {
            int i = tid + 256 * r;
            int kr = i >> 4;
            int nc = (i & 15) << 2;
            *(float4*)(&Bs[kr][nc]) = *(const float4*)(W + (size_t)(k0 + kr) * Ncols + col0 + nc);
        }
        __syncthreads();

#pragma unroll
        for (int kk = 0; kk < 32; ++kk) {
            const float4 a4 = *(const float4*)(&As[kk][ty * 4]);
            const float4 b4 = *(const float4*)(&Bs[kk][tx * 4]);
            const float av[4] = {a4.x, a4.y, a4.z, a4.w};
            const float bw[4] = {b4.x, b4.y, b4.z, b4.w};
#pragma unroll
            for (int i = 0; i < 4; ++i)
#pragma unroll
                for (int j = 0; j < 4; ++j)
                    acc[i][j] = fmaf(av[i], bw[j], acc[i][j]);
        }
        __syncthreads();
    }

#pragma unroll
    for (int i = 0; i < 4; ++i) {
        const int col = col0 + tx * 4;
        float4 v = make_float4(acc[i][0], acc[i][1], acc[i][2], acc[i][3]);
        if (bias) {
            const float4 bb = *(const float4*)(bias + col);
            v.x += bb.x; v.y += bb.y; v.z += bb.z; v.w += bb.w;
        }
        *(float4*)(Cout + (size_t)(row0 + ty * 4 + i) * Ncols + col) = v;
    }
}

// ---------------------------------------------------------------------------
extern "C" void kernel_launch(void* const* d_in, const int* in_sizes, int n_in,
                              void* d_out, int out_size, void* d_ws, size_t ws_size,
                              hipStream_t stream)
{
    (void)in_sizes; (void)n_in; (void)out_size; (void)ws_size;
    const float* x    = (const float*)d_in[0];
    const float* wq   = (const float*)d_in[1];
    const float* wk   = (const float*)d_in[2];
    const float* wv   = (const float*)d_in[3];
    const float* bv   = (const float*)d_in[4];
    const float* cq_w = (const float*)d_in[5];
    const float* cq_b = (const float*)d_in[6];
    const float* ck_w = (const float*)d_in[7];
    const float* ck_b = (const float*)d_in[8];
    const float* cv_w = (const float*)d_in[9];
    const float* cv_b = (const float*)d_in[10];
    const float* wo   = (const float*)d_in[11];
    const float* bo   = (const float*)d_in[12];
    float* out = (float*)d_out;

    char* wsb = (char*)d_ws;
    const size_t T = (size_t)B_ * N_ * C_;               // 6,291,456 elems
    unsigned short* xb  = (unsigned short*)wsb;           // 12.58 MB
    unsigned short* wqT = (unsigned short*)(wsb + 2 * T); // weights: 3 x 1.18 MB
    unsigned short* wkT = wqT + 589824;
    unsigned short* wvT = wkT + 589824;
    float* q_lin = (float*)(wsb + 2 * T + 3 * 2 * 589824);
    float* k_lin = q_lin + T;
    float* v_lin = k_lin + T;
    unsigned short* qc = (unsigned short*)(v_lin + T);
    unsigned short* kc = qc + T;
    unsigned short* vtmp = xb;                 // xb dead after GEMMs
    unsigned short* vt   = (unsigned short*)q_lin;  // q_lin dead after q-conv
    float* attn_out      = k_lin;              // k_lin dead after k-conv

    const int M = B_ * N_;

    castx_kernel<<<dim3((int)(T / 8 / 256)), 256, 0, stream>>>(x, xb);
    castwT_kernel<<<dim3(12, 12), 256, 0, stream>>>(wq, wqT);
    castwT_kernel<<<dim3(12, 12), 256, 0, stream>>>(wk, wkT);
    castwT_kernel<<<dim3(12, 12), 256, 0, stream>>>(wv, wvT);

    gemm_bf16<<<dim3(M / 64, C_ / 128), 256, 0, stream>>>(xb, wqT, nullptr, q_lin, M, C_, C_);
    gemm_bf16<<<dim3(M / 64, C_ / 128), 256, 0, stream>>>(xb, wkT, nullptr, k_lin, M, C_, C_);
    gemm_bf16<<<dim3(M / 64, C_ / 128), 256, 0, stream>>>(xb, wvT, bv,      v_lin, M, C_, C_);

    const int convBlocks = (B_ * N_ * (C_ / 4)) / 256;
    dwconv_bf16<<<convBlocks, 256, 0, stream>>>(q_lin, cq_w, cq_b, qc);
    dwconv_bf16<<<convBlocks, 256, 0, stream>>>(k_lin, ck_w, ck_b, kc);
    dwconv_bf16<<<convBlocks, 256, 0, stream>>>(v_lin, cv_w, cv_b, vtmp);

    transpose64<<<dim3(N_ / 64, B_ * H_), 256, 0, stream>>>(vtmp, vt);

    attn_mfma<<<dim3(N_ / 128, B_ * H_), 256, 0, stream>>>(qc, kc, vt, attn_out);

    gemm_kernel<<<dim3(M / 64, C_ / 64), 256, 0, stream>>>(attn_out, wo, bo, out, M, C_, C_);
}

// Round 4
// 319.990 us; speedup vs baseline: 3.3637x; 1.2713x over previous
//
#include <hip/hip_runtime.h>
#include <math.h>

static constexpr int B_ = 8, N_ = 1024, C_ = 768, H_ = 12, D_ = 64;

typedef __bf16 bf16_t;
typedef bf16_t bf16x8 __attribute__((ext_vector_type(8)));
typedef float f32x4 __attribute__((ext_vector_type(4)));

#define MFMA16(a, b, c) __builtin_amdgcn_mfma_f32_16x16x32_bf16((a), (b), (c), 0, 0, 0)

__device__ __forceinline__ unsigned short f2bf(float f) {
    unsigned u = __builtin_bit_cast(unsigned, f);
    u += 0x7FFFu + ((u >> 16) & 1u);          // round-nearest-even
    return (unsigned short)(u >> 16);
}

__device__ __forceinline__ void gload16(void* lds, const void* g) {
    __builtin_amdgcn_global_load_lds(
        (const __attribute__((address_space(1))) unsigned int*)g,
        (__attribute__((address_space(3))) unsigned int*)lds, 16, 0, 0);
}

// swizzled byte offset for [row][64 bf16] tiles (128B rows), 16B slots
__device__ __forceinline__ int swz(int row, int kslot) {
    return row * 128 + (((kslot ^ row) & 7) << 4);
}

// ---------------------------------------------------------------------------
// fp32 → bf16 cast, 8 elems/thread
// ---------------------------------------------------------------------------
__global__ __launch_bounds__(256)
void castx_kernel(const float* __restrict__ in, unsigned short* __restrict__ out)
{
    const int i = blockIdx.x * 256 + threadIdx.x;
    const float4 a = ((const float4*)in)[2 * i];
    const float4 b = ((const float4*)in)[2 * i + 1];
    uint4 o;
    o.x = f2bf(a.x) | ((unsigned)f2bf(a.y) << 16);
    o.y = f2bf(a.z) | ((unsigned)f2bf(a.w) << 16);
    o.z = f2bf(b.x) | ((unsigned)f2bf(b.y) << 16);
    o.w = f2bf(b.z) | ((unsigned)f2bf(b.w) << 16);
    ((uint4*)out)[i] = o;
}

// ---------------------------------------------------------------------------
// transpose+cast weight [768,768] fp32 -> bf16 [N][K]
// ---------------------------------------------------------------------------
__global__ __launch_bounds__(256)
void castwT_kernel(const float* __restrict__ w, unsigned short* __restrict__ wT)
{
    __shared__ float T[64][65];
    const int t = threadIdx.x;
    const int k0 = blockIdx.x * 64, n0 = blockIdx.y * 64;
    const int r = t >> 2, c0 = (t & 3) * 16;
#pragma unroll
    for (int j4 = 0; j4 < 4; ++j4) {
        const float4 v = *(const float4*)(w + (size_t)(k0 + r) * 768 + n0 + c0 + j4 * 4);
        T[r][c0 + j4 * 4 + 0] = v.x; T[r][c0 + j4 * 4 + 1] = v.y;
        T[r][c0 + j4 * 4 + 2] = v.z; T[r][c0 + j4 * 4 + 3] = v.w;
    }
    __syncthreads();
    const int nn = t >> 2;
    unsigned short o[16];
#pragma unroll
    for (int j = 0; j < 16; ++j) o[j] = f2bf(T[c0 + j][nn]);
    uint4* dst = (uint4*)(wT + (size_t)(n0 + nn) * 768 + k0 + c0);
    dst[0] = *(uint4*)(o); dst[1] = *(uint4*)(o + 8);
}

// ---------------------------------------------------------------------------
// bf16 MFMA GEMM, m97 structure: C[M,N] f32 = A[M,K]bf16 @ BT[N,K]bf16^T (+bias)
// BM=BN=128, BK=64; 4 waves (2x2), wave = 64x64 out (4x4 frags); 16x16x32 MFMA
// ---------------------------------------------------------------------------
__global__ __launch_bounds__(256)
void gemm_bf16(const unsigned short* __restrict__ A, const unsigned short* __restrict__ BT,
               const float* __restrict__ bias, float* __restrict__ Cmat,
               int M, int Ncols, int Kdim)
{
    __shared__ char As[128 * 128];    // [128 rows][64 bf16] swizzled
    __shared__ char Bs[128 * 128];

    const int tid = threadIdx.x, lane = tid & 63, w = tid >> 6;
    const int wr = w >> 1, wc = w & 1;
    const int slot = lane & 7, rsub = lane >> 3;
    const int row0 = blockIdx.x * 128, col0 = blockIdx.y * 128;

    f32x4 acc[4][4] = {};

    for (int k0 = 0; k0 < Kdim; k0 += 64) {
#pragma unroll
        for (int c = 0; c < 4; ++c) {
            const int chunk = c * 4 + w;
            const int r = chunk * 8 + rsub;
            gload16(As + chunk * 1024, A + (size_t)(row0 + r) * Kdim + k0 + 8 * (slot ^ (r & 7)));
            gload16(Bs + chunk * 1024, BT + (size_t)(col0 + r) * Kdim + k0 + 8 * (slot ^ (r & 7)));
        }
        __syncthreads();

#pragma unroll
        for (int kk = 0; kk < 2; ++kk) {
            const int kslot = kk * 4 + (lane >> 4);
            bf16x8 af[4], bf[4];
#pragma unroll
            for (int mi = 0; mi < 4; ++mi)
                af[mi] = *(const bf16x8*)(As + swz(wr * 64 + mi * 16 + (lane & 15), kslot));
#pragma unroll
            for (int ni = 0; ni < 4; ++ni)
                bf[ni] = *(const bf16x8*)(Bs + swz(wc * 64 + ni * 16 + (lane & 15), kslot));
#pragma unroll
            for (int mi = 0; mi < 4; ++mi)
#pragma unroll
                for (int ni = 0; ni < 4; ++ni)
                    acc[mi][ni] = MFMA16(af[mi], bf[ni], acc[mi][ni]);
        }
        __syncthreads();
    }

#pragma unroll
    for (int mi = 0; mi < 4; ++mi) {
        const int row = row0 + wr * 64 + mi * 16 + ((lane >> 4) << 2);
#pragma unroll
        for (int ni = 0; ni < 4; ++ni) {
            const int col = col0 + wc * 64 + ni * 16 + (lane & 15);
            const float bv_ = bias ? bias[col] : 0.f;
#pragma unroll
            for (int r = 0; r < 4; ++r)
                Cmat[(size_t)(row + r) * Ncols + col] = acc[mi][ni][r] + bv_;
        }
    }
}

// ---------------------------------------------------------------------------
// depthwise causal conv over BATCH axis, fp32 in [B,N,C] -> bf16 out [B,H,N,D]
// ---------------------------------------------------------------------------
__global__ __launch_bounds__(256)
void dwconv_bf16(const float* __restrict__ lin, const float* __restrict__ w,
                 const float* __restrict__ bias, unsigned short* __restrict__ out)
{
    const int i = blockIdx.x * 256 + threadIdx.x;
    const int c4 = i % (C_ / 4);
    const int n  = (i / (C_ / 4)) % N_;
    const int b  = i / ((C_ / 4) * N_);
    const int c  = c4 * 4;

    float4 x0 = make_float4(0.f, 0.f, 0.f, 0.f);
    float4 x1 = x0;
    if (b >= 2) x0 = *(const float4*)(lin + ((size_t)(b - 2) * N_ + n) * C_ + c);
    if (b >= 1) x1 = *(const float4*)(lin + ((size_t)(b - 1) * N_ + n) * C_ + c);
    const float4 x2 = *(const float4*)(lin + ((size_t)b * N_ + n) * C_ + c);
    const float4 bb = *(const float4*)(bias + c);

    float4 y;
    y.x = fmaf(w[(c + 0) * 3 + 0], x0.x, fmaf(w[(c + 0) * 3 + 1], x1.x, fmaf(w[(c + 0) * 3 + 2], x2.x, bb.x)));
    y.y = fmaf(w[(c + 1) * 3 + 0], x0.y, fmaf(w[(c + 1) * 3 + 1], x1.y, fmaf(w[(c + 1) * 3 + 2], x2.y, bb.y)));
    y.z = fmaf(w[(c + 2) * 3 + 0], x0.z, fmaf(w[(c + 2) * 3 + 1], x1.z, fmaf(w[(c + 2) * 3 + 2], x2.z, bb.z)));
    y.w = fmaf(w[(c + 3) * 3 + 0], x0.w, fmaf(w[(c + 3) * 3 + 1], x1.w, fmaf(w[(c + 3) * 3 + 2], x2.w, bb.w)));

    const int h = c / D_, d = c % D_;
    ushort4 o;
    o.x = f2bf(y.x); o.y = f2bf(y.y); o.z = f2bf(y.z); o.w = f2bf(y.w);
    *(ushort4*)(out + (((size_t)b * H_ + h) * N_ + n) * D_ + d) = o;
}

// ---------------------------------------------------------------------------
// bf16 transpose [BH,N,64] -> [BH,64,N], 64x64 tiles
// ---------------------------------------------------------------------------
__global__ __launch_bounds__(256)
void transpose64(const unsigned short* __restrict__ in, unsigned short* __restrict__ out)
{
    __shared__ unsigned short T[64][67];
    const int t = threadIdx.x;
    const int bh = blockIdx.y, n0 = blockIdx.x * 64;
    const int r = t >> 2, c0 = (t & 3) * 16;

    const uint4* src = (const uint4*)(in + ((size_t)bh * N_ + n0 + r) * 64 + c0);
    unsigned short tmp[16];
    *(uint4*)(tmp) = src[0];
    *(uint4*)(tmp + 8) = src[1];
#pragma unroll
    for (int j = 0; j < 16; ++j) T[r][c0 + j] = tmp[j];
    __syncthreads();

    const int d = t >> 2;
    unsigned short o[16];
#pragma unroll
    for (int j = 0; j < 16; ++j) o[j] = T[c0 + j][d];
    uint4* dst = (uint4*)(out + ((size_t)bh * 64 + d) * N_ + n0 + c0);
    dst[0] = *(uint4*)(o); dst[1] = *(uint4*)(o + 8);
}

// ---------------------------------------------------------------------------
// MFMA flash attention. Q,K: [BH,N,64] bf16; Vt: [BH,64,N] bf16
// O: [B,N,C] bf16 (feeds projection GEMM directly)
// Block: 128 q-rows of one bh; 4 waves x 32 rows; KV tiles 64, double-buffered.
// ---------------------------------------------------------------------------
__global__ __launch_bounds__(256)
void attn_mfma(const unsigned short* __restrict__ Qg, const unsigned short* __restrict__ Kg,
               const unsigned short* __restrict__ Vtg, unsigned short* __restrict__ Og)
{
    __shared__ char Pb[16384];      // Q staging, then per-wave P tiles
    __shared__ char Kb[2][8192];
    __shared__ char Vb[2][8192];

    const int tid = threadIdx.x, lane = tid & 63, w = tid >> 6;
    const int slot = lane & 7, rsub = lane >> 3;
    const int bh = blockIdx.y, b = bh / H_, h = bh % H_;
    const int q0 = blockIdx.x * 128;

    const unsigned short* Qp = Qg + (size_t)bh * N_ * 64;
    const unsigned short* Kp = Kg + (size_t)bh * N_ * 64;
    const unsigned short* Vp = Vtg + (size_t)bh * 64 * N_;

    // stage Q (16KB) into Pb
#pragma unroll
    for (int c = 0; c < 4; ++c) {
        const int chunk = c * 4 + w;
        const int r = chunk * 8 + rsub;
        gload16(Pb + chunk * 1024, Qp + (size_t)(q0 + r) * 64 + 8 * (slot ^ (r & 7)));
    }
    // stage K,V tile 0 into buf 0
#pragma unroll
    for (int c = 0; c < 2; ++c) {
        const int chunk = c * 4 + w;
        const int r = chunk * 8 + rsub;
        gload16(Kb[0] + chunk * 1024, Kp + (size_t)r * 64 + 8 * (slot ^ (r & 7)));
        gload16(Vb[0] + chunk * 1024, Vp + (size_t)r * N_ + 8 * (slot ^ (r & 7)));
    }
    __syncthreads();

    // Q fragments (held whole kernel)
    bf16x8 qf[2][2];
#pragma unroll
    for (int mi = 0; mi < 2; ++mi)
#pragma unroll
        for (int kk = 0; kk < 2; ++kk)
            qf[mi][kk] = *(const bf16x8*)(Pb + swz(w * 32 + mi * 16 + (lane & 15), kk * 4 + (lane >> 4)));

    f32x4 o[2][4] = {};
    float mrow[2][4], lrow[2][4];
#pragma unroll
    for (int mi = 0; mi < 2; ++mi)
#pragma unroll
        for (int r = 0; r < 4; ++r) { mrow[mi][r] = -1e30f; lrow[mi][r] = 0.f; }

    int buf = 0;
    for (int kt = 0; kt < N_ / 64; ++kt) {
        if (kt < N_ / 64 - 1) {
            const int nb = buf ^ 1;
#pragma unroll
            for (int c = 0; c < 2; ++c) {
                const int chunk = c * 4 + w;
                const int r = chunk * 8 + rsub;
                gload16(Kb[nb] + chunk * 1024, Kp + (size_t)((kt + 1) * 64 + r) * 64 + 8 * (slot ^ (r & 7)));
                gload16(Vb[nb] + chunk * 1024, Vp + (size_t)r * N_ + (kt + 1) * 64 + 8 * (slot ^ (r & 7)));
            }
        }

        // ---- S = Q K^T (16 MFMA) ----
        f32x4 s[2][4] = {};
#pragma unroll
        for (int kk = 0; kk < 2; ++kk) {
            const int kslot = kk * 4 + (lane >> 4);
            bf16x8 kf[4];
#pragma unroll
            for (int ni = 0; ni < 4; ++ni)
                kf[ni] = *(const bf16x8*)(Kb[buf] + swz(ni * 16 + (lane & 15), kslot));
#pragma unroll
            for (int mi = 0; mi < 2; ++mi)
#pragma unroll
                for (int ni = 0; ni < 4; ++ni)
                    s[mi][ni] = MFMA16(qf[mi][kk], kf[ni], s[mi][ni]);
        }

        // ---- online softmax + P write (wave-private region of Pb) ----
#pragma unroll
        for (int mi = 0; mi < 2; ++mi) {
            float pv[4][4];     // [r][ni]
#pragma unroll
            for (int r = 0; r < 4; ++r) {
                const float a0 = s[mi][0][r] * 0.125f, a1 = s[mi][1][r] * 0.125f;
                const float a2 = s[mi][2][r] * 0.125f, a3 = s[mi][3][r] * 0.125f;
                pv[r][0] = a0; pv[r][1] = a1; pv[r][2] = a2; pv[r][3] = a3;
                float m0 = fmaxf(fmaxf(a0, a1), fmaxf(a2, a3));
#pragma unroll
                for (int mk = 1; mk < 16; mk <<= 1) m0 = fmaxf(m0, __shfl_xor(m0, mk));
                const float mold = mrow[mi][r];
                const float mnew = fmaxf(mold, m0);
                const float f = __expf(mold - mnew);
                mrow[mi][r] = mnew;
                float ssum = 0.f;
#pragma unroll
                for (int ni = 0; ni < 4; ++ni) {
                    const float e = __expf(pv[r][ni] - mnew);
                    pv[r][ni] = e; ssum += e;
                }
#pragma unroll
                for (int mk = 1; mk < 16; mk <<= 1) ssum += __shfl_xor(ssum, mk);
                lrow[mi][r] = lrow[mi][r] * f + ssum;
#pragma unroll
                for (int nd = 0; nd < 4; ++nd) o[mi][nd][r] *= f;
            }
            const int prow_base = w * 32 + mi * 16 + ((lane >> 4) << 2);
#pragma unroll
            for (int r = 0; r < 4; ++r) {
                const int m = prow_base + r;
                const int rowoff = m * 128, sw = (m & 7) << 4;
#pragma unroll
                for (int ni = 0; ni < 4; ++ni) {
                    const int col = ni * 16 + (lane & 15);
                    *(unsigned short*)(Pb + rowoff + ((col * 2) ^ sw)) = f2bf(pv[r][ni]);
                }
            }
        }

        // ---- O += P V (16 MFMA) ----
#pragma unroll
        for (int kk = 0; kk < 2; ++kk) {
            const int kslot = kk * 4 + (lane >> 4);
            bf16x8 pa[2], vf[4];
#pragma unroll
            for (int mi = 0; mi < 2; ++mi)
                pa[mi] = *(const bf16x8*)(Pb + swz(w * 32 + mi * 16 + (lane & 15), kslot));
#pragma unroll
            for (int nd = 0; nd < 4; ++nd)
                vf[nd] = *(const bf16x8*)(Vb[buf] + swz(nd * 16 + (lane & 15), kslot));
#pragma unroll
            for (int mi = 0; mi < 2; ++mi)
#pragma unroll
                for (int nd = 0; nd < 4; ++nd)
                    o[mi][nd] = MFMA16(pa[mi], vf[nd], o[mi][nd]);
        }

        __syncthreads();
        buf ^= 1;
    }

    // epilogue: normalize, write [B,N,C] bf16 (c = h*64 + d)
#pragma unroll
    for (int mi = 0; mi < 2; ++mi)
#pragma unroll
        for (int r = 0; r < 4; ++r) {
            const float inv = 1.0f / lrow[mi][r];
            const int qrow = q0 + w * 32 + mi * 16 + ((lane >> 4) << 2) + r;
            unsigned short* orow = Og + ((size_t)b * N_ + qrow) * C_ + h * D_ + (lane & 15);
#pragma unroll
            for (int nd = 0; nd < 4; ++nd) orow[nd * 16] = f2bf(o[mi][nd][r] * inv);
        }
}

// ---------------------------------------------------------------------------
extern "C" void kernel_launch(void* const* d_in, const int* in_sizes, int n_in,
                              void* d_out, int out_size, void* d_ws, size_t ws_size,
                              hipStream_t stream)
{
    (void)in_sizes; (void)n_in; (void)out_size; (void)ws_size;
    const float* x    = (const float*)d_in[0];
    const float* wq   = (const float*)d_in[1];
    const float* wk   = (const float*)d_in[2];
    const float* wv   = (const float*)d_in[3];
    const float* bv   = (const float*)d_in[4];
    const float* cq_w = (const float*)d_in[5];
    const float* cq_b = (const float*)d_in[6];
    const float* ck_w = (const float*)d_in[7];
    const float* ck_b = (const float*)d_in[8];
    const float* cv_w = (const float*)d_in[9];
    const float* cv_b = (const float*)d_in[10];
    const float* wo   = (const float*)d_in[11];
    const float* bo   = (const float*)d_in[12];
    float* out = (float*)d_out;

    char* wsb = (char*)d_ws;
    const size_t T = (size_t)B_ * N_ * C_;               // 6,291,456 elems
    const size_t WB = 2 * 589824;                         // one bf16 768x768
    unsigned short* xb  = (unsigned short*)wsb;           // 2T bytes
    unsigned short* wqT = (unsigned short*)(wsb + 2 * T);
    unsigned short* wkT = wqT + 589824;
    unsigned short* wvT = wkT + 589824;
    float* q_lin = (float*)(wsb + 2 * T + 3 * WB);        // 4T bytes
    float* k_lin = q_lin + T;                             // 4T bytes
    float* v_lin = k_lin + T;                             // 4T bytes
    unsigned short* qc = (unsigned short*)(v_lin + T);    // 2T bytes
    unsigned short* kc = qc + T;                          // 2T bytes
    unsigned short* vtmp = xb;                            // xb dead after GEMMs
    unsigned short* vt   = (unsigned short*)q_lin;        // q_lin dead after q-conv
    unsigned short* attn_out = (unsigned short*)k_lin;    // k_lin dead after k-conv
    unsigned short* woT = (unsigned short*)((char*)k_lin + 2 * T);  // fits in k_lin's back half

    const int M = B_ * N_;

    castx_kernel<<<dim3((int)(T / 8 / 256)), 256, 0, stream>>>(x, xb);
    castwT_kernel<<<dim3(12, 12), 256, 0, stream>>>(wq, wqT);
    castwT_kernel<<<dim3(12, 12), 256, 0, stream>>>(wk, wkT);
    castwT_kernel<<<dim3(12, 12), 256, 0, stream>>>(wv, wvT);

    gemm_bf16<<<dim3(M / 128, C_ / 128), 256, 0, stream>>>(xb, wqT, nullptr, q_lin, M, C_, C_);
    gemm_bf16<<<dim3(M / 128, C_ / 128), 256, 0, stream>>>(xb, wkT, nullptr, k_lin, M, C_, C_);
    gemm_bf16<<<dim3(M / 128, C_ / 128), 256, 0, stream>>>(xb, wvT, bv,      v_lin, M, C_, C_);

    const int convBlocks = (B_ * N_ * (C_ / 4)) / 256;
    dwconv_bf16<<<convBlocks, 256, 0, stream>>>(q_lin, cq_w, cq_b, qc);
    dwconv_bf16<<<convBlocks, 256, 0, stream>>>(k_lin, ck_w, ck_b, kc);
    dwconv_bf16<<<convBlocks, 256, 0, stream>>>(v_lin, cv_w, cv_b, vtmp);

    transpose64<<<dim3(N_ / 64, B_ * H_), 256, 0, stream>>>(vtmp, vt);
    castwT_kernel<<<dim3(12, 12), 256, 0, stream>>>(wo, woT);   // k_lin dead now

    attn_mfma<<<dim3(N_ / 128, B_ * H_), 256, 0, stream>>>(qc, kc, vt, attn_out);

    gemm_bf16<<<dim3(M / 128, C_ / 128), 256, 0, stream>>>(attn_out, woT, bo, out, M, C_, C_);
}

// Round 6
// 308.293 us; speedup vs baseline: 3.4914x; 1.0379x over previous
//
#include <hip/hip_runtime.h>
#include <math.h>

static constexpr int B_ = 8, N_ = 1024, C_ = 768, H_ = 12, D_ = 64;

typedef __bf16 bf16_t;
typedef bf16_t bf16x8 __attribute__((ext_vector_type(8)));
typedef float f32x4 __attribute__((ext_vector_type(4)));

#define MFMA32(a, b, c) __builtin_amdgcn_mfma_f32_16x16x32_bf16((a), (b), (c), 0, 0, 0)

__device__ __forceinline__ unsigned short f2bf(float f) {
    unsigned u = __builtin_bit_cast(unsigned, f);
    u += 0x7FFFu + ((u >> 16) & 1u);
    return (unsigned short)(u >> 16);
}

__device__ __forceinline__ float bf2f(unsigned short u) {
    return __builtin_bit_cast(float, (unsigned)u << 16);
}

__device__ __forceinline__ void gload16(void* lds, const void* g) {
    __builtin_amdgcn_global_load_lds(
        (const __attribute__((address_space(1))) unsigned int*)g,
        (__attribute__((address_space(3))) unsigned int*)lds, 16, 0, 0);
}

// swizzled byte offset for [row][64 bf16] tiles (128B rows), 16B slots
__device__ __forceinline__ int swz(int row, int kslot) {
    return row * 128 + (((kslot ^ row) & 7) << 4);
}

// ---------------------------------------------------------------------------
// fp32 -> bf16 cast, 8 elems/thread
// ---------------------------------------------------------------------------
__global__ __launch_bounds__(256)
void castx_kernel(const float* __restrict__ in, unsigned short* __restrict__ out)
{
    const int i = blockIdx.x * 256 + threadIdx.x;
    const float4 a = ((const float4*)in)[2 * i];
    const float4 b = ((const float4*)in)[2 * i + 1];
    uint4 o;
    o.x = f2bf(a.x) | ((unsigned)f2bf(a.y) << 16);
    o.y = f2bf(a.z) | ((unsigned)f2bf(a.w) << 16);
    o.z = f2bf(b.x) | ((unsigned)f2bf(b.y) << 16);
    o.w = f2bf(b.z) | ((unsigned)f2bf(b.w) << 16);
    ((uint4*)out)[i] = o;
}

// ---------------------------------------------------------------------------
// transpose+cast 4 weights [768,768] fp32 -> bf16 [N][K], z-selected
// ---------------------------------------------------------------------------
__global__ __launch_bounds__(256)
void castwT4_kernel(const float* w0, const float* w1, const float* w2, const float* w3,
                    unsigned short* o0, unsigned short* o1,
                    unsigned short* o2, unsigned short* o3)
{
    const float* w; unsigned short* wT;
    switch (blockIdx.z) {
        case 0:  w = w0; wT = o0; break;
        case 1:  w = w1; wT = o1; break;
        case 2:  w = w2; wT = o2; break;
        default: w = w3; wT = o3; break;
    }
    __shared__ float T[64][65];
    const int t = threadIdx.x;
    const int k0 = blockIdx.x * 64, n0 = blockIdx.y * 64;
    const int r = t >> 2, c0 = (t & 3) * 16;
#pragma unroll
    for (int j4 = 0; j4 < 4; ++j4) {
        const float4 v = *(const float4*)(w + (size_t)(k0 + r) * 768 + n0 + c0 + j4 * 4);
        T[r][c0 + j4 * 4 + 0] = v.x; T[r][c0 + j4 * 4 + 1] = v.y;
        T[r][c0 + j4 * 4 + 2] = v.z; T[r][c0 + j4 * 4 + 3] = v.w;
    }
    __syncthreads();
    const int nn = t >> 2;
    unsigned short o[16];
#pragma unroll
    for (int j = 0; j < 16; ++j) o[j] = f2bf(T[c0 + j][nn]);
    uint4* dst = (uint4*)(wT + (size_t)(n0 + nn) * 768 + k0 + c0);
    dst[0] = *(uint4*)(o); dst[1] = *(uint4*)(o + 8);
}

// ---------------------------------------------------------------------------
// bf16 MFMA GEMM core (m97 structure): C = A[M,K] @ BT[N,K]^T (+bias)
// BM=BN=128, BK=64; 4 waves (2x2); 16x16x32 MFMA. OutT = ushort(bf16) or float.
// ---------------------------------------------------------------------------
template <typename OutT>
__device__ __forceinline__ void gemm_body(const unsigned short* __restrict__ A,
                                          const unsigned short* __restrict__ BT,
                                          const float* __restrict__ bias,
                                          OutT* __restrict__ Cmat,
                                          int Ncols, int Kdim, int row0, int col0)
{
    __shared__ char As[128 * 128];
    __shared__ char Bs[128 * 128];

    const int tid = threadIdx.x, lane = tid & 63, w = tid >> 6;
    const int wr = w >> 1, wc = w & 1;
    const int slot = lane & 7, rsub = lane >> 3;

    f32x4 acc[4][4] = {};

    for (int k0 = 0; k0 < Kdim; k0 += 64) {
#pragma unroll
        for (int c = 0; c < 4; ++c) {
            const int chunk = c * 4 + w;
            const int r = chunk * 8 + rsub;
            gload16(As + chunk * 1024, A + (size_t)(row0 + r) * Kdim + k0 + 8 * (slot ^ (r & 7)));
            gload16(Bs + chunk * 1024, BT + (size_t)(col0 + r) * Kdim + k0 + 8 * (slot ^ (r & 7)));
        }
        __syncthreads();

#pragma unroll
        for (int kk = 0; kk < 2; ++kk) {
            const int kslot = kk * 4 + (lane >> 4);
            bf16x8 af[4], bf[4];
#pragma unroll
            for (int mi = 0; mi < 4; ++mi)
                af[mi] = *(const bf16x8*)(As + swz(wr * 64 + mi * 16 + (lane & 15), kslot));
#pragma unroll
            for (int ni = 0; ni < 4; ++ni)
                bf[ni] = *(const bf16x8*)(Bs + swz(wc * 64 + ni * 16 + (lane & 15), kslot));
#pragma unroll
            for (int mi = 0; mi < 4; ++mi)
#pragma unroll
                for (int ni = 0; ni < 4; ++ni)
                    acc[mi][ni] = MFMA32(af[mi], bf[ni], acc[mi][ni]);
        }
        __syncthreads();
    }

#pragma unroll
    for (int mi = 0; mi < 4; ++mi) {
        const int row = row0 + wr * 64 + mi * 16 + ((lane >> 4) << 2);
#pragma unroll
        for (int ni = 0; ni < 4; ++ni) {
            const int col = col0 + wc * 64 + ni * 16 + (lane & 15);
            const float bv_ = bias ? bias[col] : 0.f;
#pragma unroll
            for (int r = 0; r < 4; ++r) {
                const float v = acc[mi][ni][r] + bv_;
                if constexpr (sizeof(OutT) == 2)
                    Cmat[(size_t)(row + r) * Ncols + col] = (OutT)f2bf(v);
                else
                    Cmat[(size_t)(row + r) * Ncols + col] = v;
            }
        }
    }
}

// merged QKV projection: grid (M/128, 18); y selects q/k/v and col-tile
__global__ __launch_bounds__(256)
void gemm_qkv(const unsigned short* __restrict__ xb,
              const unsigned short* __restrict__ wqT, const unsigned short* __restrict__ wkT,
              const unsigned short* __restrict__ wvT, const float* __restrict__ bv,
              unsigned short* __restrict__ q_lin, unsigned short* __restrict__ k_lin,
              unsigned short* __restrict__ v_lin)
{
    const int by = blockIdx.y, sel = by / 6, colt = by % 6;
    const unsigned short* BT; unsigned short* dst; const float* bias = nullptr;
    if (sel == 0)      { BT = wqT; dst = q_lin; }
    else if (sel == 1) { BT = wkT; dst = k_lin; }
    else               { BT = wvT; dst = v_lin; bias = bv; }
    gemm_body<unsigned short>(xb, BT, bias, dst, C_, C_, blockIdx.x * 128, colt * 128);
}

__global__ __launch_bounds__(256)
void gemm_proj(const unsigned short* __restrict__ A, const unsigned short* __restrict__ BT,
               const float* __restrict__ bias, float* __restrict__ Cmat)
{
    gemm_body<float>(A, BT, bias, Cmat, C_, C_, blockIdx.x * 128, blockIdx.y * 128);
}

// ---------------------------------------------------------------------------
// q/k depthwise causal conv over BATCH axis; bf16 in [B,N,C] -> bf16 [BH,N,64]
// ---------------------------------------------------------------------------
__global__ __launch_bounds__(256)
void dwconv_qk(const unsigned short* __restrict__ qlin, const unsigned short* __restrict__ klin,
               const float* __restrict__ cq_w, const float* __restrict__ cq_b,
               const float* __restrict__ ck_w, const float* __restrict__ ck_b,
               unsigned short* __restrict__ qc, unsigned short* __restrict__ kc)
{
    const unsigned short* lin; const float* w; const float* bias;
    unsigned short* out;
    if (blockIdx.y == 0) { lin = qlin; w = cq_w; bias = cq_b; out = qc; }
    else                 { lin = klin; w = ck_w; bias = ck_b; out = kc; }

    const int i = blockIdx.x * 256 + threadIdx.x;
    const int c8 = i % (C_ / 8);
    const int n  = (i / (C_ / 8)) % N_;
    const int b  = i / ((C_ / 8) * N_);
    const int c  = c8 * 8;

    const uint4 z4 = make_uint4(0, 0, 0, 0);
    const uint4 x0 = (b >= 2) ? *(const uint4*)(lin + ((size_t)(b - 2) * N_ + n) * C_ + c) : z4;
    const uint4 x1 = (b >= 1) ? *(const uint4*)(lin + ((size_t)(b - 1) * N_ + n) * C_ + c) : z4;
    const uint4 x2 = *(const uint4*)(lin + ((size_t)b * N_ + n) * C_ + c);
    const unsigned short* u0 = (const unsigned short*)&x0;
    const unsigned short* u1 = (const unsigned short*)&x1;
    const unsigned short* u2 = (const unsigned short*)&x2;

    unsigned short y[8];
#pragma unroll
    for (int j = 0; j < 8; ++j) {
        const float v = w[(c + j) * 3 + 0] * bf2f(u0[j]) +
                        w[(c + j) * 3 + 1] * bf2f(u1[j]) +
                        w[(c + j) * 3 + 2] * bf2f(u2[j]) + bias[c + j];
        y[j] = f2bf(v);
    }
    const int h = c8 >> 3, d0 = (c8 & 7) * 8;
    *(uint4*)(out + (((size_t)b * H_ + h) * N_ + n) * 64 + d0) = *(uint4*)y;
}

// ---------------------------------------------------------------------------
// v path: conv over batch + transpose, bf16 [B,N,C] -> vt [BH,64,N]
// ---------------------------------------------------------------------------
__global__ __launch_bounds__(256)
void conv_v_transpose(const unsigned short* __restrict__ vlin, const float* __restrict__ w,
                      const float* __restrict__ bias, unsigned short* __restrict__ vt)
{
    __shared__ unsigned short T[64][72];
    const int t = threadIdx.x;
    const int n0 = blockIdx.x * 64, bh = blockIdx.y;
    const int b = bh / H_, h = bh % H_;
    const int r = t >> 2, c0 = (t & 3) * 16;
    const int cbase = h * 64 + c0;

    float acc[16];
#pragma unroll
    for (int i = 0; i < 16; ++i) acc[i] = bias[cbase + i];
#pragma unroll
    for (int j = 0; j < 3; ++j) {
        const int bb = b - 2 + j;
        if (bb < 0) continue;
        const unsigned short* src = vlin + ((size_t)bb * N_ + n0 + r) * C_ + cbase;
        const uint4 va = *(const uint4*)src;
        const uint4 vb2 = *(const uint4*)(src + 8);
        const unsigned short* u = (const unsigned short*)&va;
        const unsigned short* u2 = (const unsigned short*)&vb2;
#pragma unroll
        for (int i = 0; i < 8; ++i)  acc[i]     += w[(cbase + i) * 3 + j] * bf2f(u[i]);
#pragma unroll
        for (int i = 0; i < 8; ++i)  acc[8 + i] += w[(cbase + 8 + i) * 3 + j] * bf2f(u2[i]);
    }
    unsigned short tmp[16];
#pragma unroll
    for (int i = 0; i < 16; ++i) tmp[i] = f2bf(acc[i]);
    *(uint4*)&T[r][c0] = *(uint4*)tmp;
    *(uint4*)&T[r][c0 + 8] = *(uint4*)(tmp + 8);
    __syncthreads();

    const int d = t >> 2;
    unsigned short o[16];
#pragma unroll
    for (int i = 0; i < 16; ++i) o[i] = T[c0 + i][d];
    uint4* dst = (uint4*)(vt + ((size_t)bh * 64 + d) * N_ + n0 + c0);
    dst[0] = *(uint4*)o; dst[1] = *(uint4*)(o + 8);
}

// ---------------------------------------------------------------------------
// MFMA flash attention (round-4 verified body). Q,K: [BH,N,64]; Vt: [BH,64,N]
// O: [B,N,C] bf16. Block: 128 q-rows; 4 waves x 32 rows; KV tiles 64, dbuf.
// Grid: 768 blocks 1-D with XCD-bijective remap (head's K/V pinned to one L2).
// ---------------------------------------------------------------------------
__global__ __launch_bounds__(256)
void attn_mfma(const unsigned short* __restrict__ Qg, const unsigned short* __restrict__ Kg,
               const unsigned short* __restrict__ Vtg, unsigned short* __restrict__ Og)
{
    __shared__ char Pb[16384];      // Q staging, then per-wave P tiles
    __shared__ char Kb[2][8192];
    __shared__ char Vb[2][8192];

    const int tid = threadIdx.x, lane = tid & 63, w = tid >> 6;
    const int slot = lane & 7, rsub = lane >> 3;

    const int id = blockIdx.x;
    const int bh = (id & 7) * 12 + ((id >> 3) % 12);   // all 8 q-blocks of a head -> same XCD
    const int q0 = (id / 96) * 128;
    const int b = bh / H_, h = bh % H_;

    const unsigned short* Qp = Qg + (size_t)bh * N_ * 64;
    const unsigned short* Kp = Kg + (size_t)bh * N_ * 64;
    const unsigned short* Vp = Vtg + (size_t)bh * 64 * N_;

    // stage Q (16KB) into Pb
#pragma unroll
    for (int c = 0; c < 4; ++c) {
        const int chunk = c * 4 + w;
        const int r = chunk * 8 + rsub;
        gload16(Pb + chunk * 1024, Qp + (size_t)(q0 + r) * 64 + 8 * (slot ^ (r & 7)));
    }
    // stage K,V tile 0 into buf 0
#pragma unroll
    for (int c = 0; c < 2; ++c) {
        const int chunk = c * 4 + w;
        const int r = chunk * 8 + rsub;
        gload16(Kb[0] + chunk * 1024, Kp + (size_t)r * 64 + 8 * (slot ^ (r & 7)));
        gload16(Vb[0] + chunk * 1024, Vp + (size_t)r * N_ + 8 * (slot ^ (r & 7)));
    }
    __syncthreads();

    // Q fragments (held whole kernel)
    bf16x8 qf[2][2];
#pragma unroll
    for (int mi = 0; mi < 2; ++mi)
#pragma unroll
        for (int kk = 0; kk < 2; ++kk)
            qf[mi][kk] = *(const bf16x8*)(Pb + swz(w * 32 + mi * 16 + (lane & 15), kk * 4 + (lane >> 4)));

    f32x4 o[2][4] = {};
    float mrow[2][4], lrow[2][4];
#pragma unroll
    for (int mi = 0; mi < 2; ++mi)
#pragma unroll
        for (int r = 0; r < 4; ++r) { mrow[mi][r] = -1e30f; lrow[mi][r] = 0.f; }

    int buf = 0;
    for (int kt = 0; kt < N_ / 64; ++kt) {
        if (kt < N_ / 64 - 1) {
            const int nb = buf ^ 1;
#pragma unroll
            for (int c = 0; c < 2; ++c) {
                const int chunk = c * 4 + w;
                const int r = chunk * 8 + rsub;
                gload16(Kb[nb] + chunk * 1024, Kp + (size_t)((kt + 1) * 64 + r) * 64 + 8 * (slot ^ (r & 7)));
                gload16(Vb[nb] + chunk * 1024, Vp + (size_t)r * N_ + (kt + 1) * 64 + 8 * (slot ^ (r & 7)));
            }
        }

        // ---- S = Q K^T (16 MFMA) ----
        f32x4 s[2][4] = {};
#pragma unroll
        for (int kk = 0; kk < 2; ++kk) {
            const int kslot = kk * 4 + (lane >> 4);
            bf16x8 kf[4];
#pragma unroll
            for (int ni = 0; ni < 4; ++ni)
                kf[ni] = *(const bf16x8*)(Kb[buf] + swz(ni * 16 + (lane & 15), kslot));
#pragma unroll
            for (int mi = 0; mi < 2; ++mi)
#pragma unroll
                for (int ni = 0; ni < 4; ++ni)
                    s[mi][ni] = MFMA32(qf[mi][kk], kf[ni], s[mi][ni]);
        }

        // ---- online softmax + P write (wave-private region of Pb) ----
#pragma unroll
        for (int mi = 0; mi < 2; ++mi) {
            float pv[4][4];     // [r][ni]
#pragma unroll
            for (int r = 0; r < 4; ++r) {
                const float a0 = s[mi][0][r] * 0.125f, a1 = s[mi][1][r] * 0.125f;
                const float a2 = s[mi][2][r] * 0.125f, a3 = s[mi][3][r] * 0.125f;
                pv[r][0] = a0; pv[r][1] = a1; pv[r][2] = a2; pv[r][3] = a3;
                float m0 = fmaxf(fmaxf(a0, a1), fmaxf(a2, a3));
#pragma unroll
                for (int mk = 1; mk < 16; mk <<= 1) m0 = fmaxf(m0, __shfl_xor(m0, mk));
                const float mold = mrow[mi][r];
                const float mnew = fmaxf(mold, m0);
                const float f = __expf(mold - mnew);
                mrow[mi][r] = mnew;
                float ssum = 0.f;
#pragma unroll
                for (int ni = 0; ni < 4; ++ni) {
                    const float e = __expf(pv[r][ni] - mnew);
                    pv[r][ni] = e; ssum += e;
                }
#pragma unroll
                for (int mk = 1; mk < 16; mk <<= 1) ssum += __shfl_xor(ssum, mk);
                lrow[mi][r] = lrow[mi][r] * f + ssum;
#pragma unroll
                for (int nd = 0; nd < 4; ++nd) o[mi][nd][r] *= f;
            }
            const int prow_base = w * 32 + mi * 16 + ((lane >> 4) << 2);
#pragma unroll
            for (int r = 0; r < 4; ++r) {
                const int m = prow_base + r;
                const int rowoff = m * 128, sw = (m & 7) << 4;
#pragma unroll
                for (int ni = 0; ni < 4; ++ni) {
                    const int col = ni * 16 + (lane & 15);
                    *(unsigned short*)(Pb + rowoff + ((col * 2) ^ sw)) = f2bf(pv[r][ni]);
                }
            }
        }

        // ---- O += P V (16 MFMA) ----
#pragma unroll
        for (int kk = 0; kk < 2; ++kk) {
            const int kslot = kk * 4 + (lane >> 4);
            bf16x8 pa[2], vf[4];
#pragma unroll
            for (int mi = 0; mi < 2; ++mi)
                pa[mi] = *(const bf16x8*)(Pb + swz(w * 32 + mi * 16 + (lane & 15), kslot));
#pragma unroll
            for (int nd = 0; nd < 4; ++nd)
                vf[nd] = *(const bf16x8*)(Vb[buf] + swz(nd * 16 + (lane & 15), kslot));
#pragma unroll
            for (int mi = 0; mi < 2; ++mi)
#pragma unroll
                for (int nd = 0; nd < 4; ++nd)
                    o[mi][nd] = MFMA32(pa[mi], vf[nd], o[mi][nd]);
        }

        __syncthreads();
        buf ^= 1;
    }

    // epilogue: normalize, write [B,N,C] bf16 (c = h*64 + d)
#pragma unroll
    for (int mi = 0; mi < 2; ++mi)
#pragma unroll
        for (int r = 0; r < 4; ++r) {
            const float inv = 1.0f / lrow[mi][r];
            const int qrow = q0 + w * 32 + mi * 16 + ((lane >> 4) << 2) + r;
            unsigned short* orow = Og + ((size_t)b * N_ + qrow) * C_ + h * D_ + (lane & 15);
#pragma unroll
            for (int nd = 0; nd < 4; ++nd) orow[nd * 16] = f2bf(o[mi][nd][r] * inv);
        }
}

// ---------------------------------------------------------------------------
extern "C" void kernel_launch(void* const* d_in, const int* in_sizes, int n_in,
                              void* d_out, int out_size, void* d_ws, size_t ws_size,
                              hipStream_t stream)
{
    (void)in_sizes; (void)n_in; (void)out_size; (void)ws_size;
    const float* x    = (const float*)d_in[0];
    const float* wq   = (const float*)d_in[1];
    const float* wk   = (const float*)d_in[2];
    const float* wv   = (const float*)d_in[3];
    const float* bv   = (const float*)d_in[4];
    const float* cq_w = (const float*)d_in[5];
    const float* cq_b = (const float*)d_in[6];
    const float* ck_w = (const float*)d_in[7];
    const float* ck_b = (const float*)d_in[8];
    const float* cv_w = (const float*)d_in[9];
    const float* cv_b = (const float*)d_in[10];
    const float* wo   = (const float*)d_in[11];
    const float* bo   = (const float*)d_in[12];
    float* out = (float*)d_out;

    char* wsb = (char*)d_ws;
    const size_t T  = (size_t)B_ * N_ * C_;       // 6,291,456 elems
    const size_t WB = (size_t)2 * 589824;         // one bf16 768x768
    unsigned short* xb  = (unsigned short*)wsb;                      // 2T B
    unsigned short* wqT = (unsigned short*)(wsb + 2 * T);
    unsigned short* wkT = wqT + 589824;
    unsigned short* wvT = wkT + 589824;
    unsigned short* woT = wvT + 589824;
    char* p = wsb + 2 * T + 4 * WB;
    unsigned short* q_lin = (unsigned short*)p;          p += 2 * T;
    unsigned short* k_lin = (unsigned short*)p;          p += 2 * T;
    unsigned short* v_lin = (unsigned short*)p;          p += 2 * T;
    unsigned short* qc    = (unsigned short*)p;          p += 2 * T;
    unsigned short* kc    = (unsigned short*)p;          p += 2 * T;
    unsigned short* vt    = (unsigned short*)p;          p += 2 * T;
    unsigned short* attn_out = xb;                 // xb dead after gemm_qkv

    const int M = B_ * N_;

    castx_kernel<<<dim3((int)(T / 8 / 256)), 256, 0, stream>>>(x, xb);
    castwT4_kernel<<<dim3(12, 12, 4), 256, 0, stream>>>(wq, wk, wv, wo, wqT, wkT, wvT, woT);

    gemm_qkv<<<dim3(M / 128, 18), 256, 0, stream>>>(xb, wqT, wkT, wvT, bv, q_lin, k_lin, v_lin);

    dwconv_qk<<<dim3((int)(T / 8 / 256), 2), 256, 0, stream>>>(
        q_lin, k_lin, cq_w, cq_b, ck_w, ck_b, qc, kc);
    conv_v_transpose<<<dim3(N_ / 64, B_ * H_), 256, 0, stream>>>(v_lin, cv_w, cv_b, vt);

    attn_mfma<<<dim3(768), 256, 0, stream>>>(qc, kc, vt, attn_out);

    gemm_proj<<<dim3(M / 128, C_ / 128), 256, 0, stream>>>(attn_out, woT, bo, out);
}

// Round 7
// 277.803 us; speedup vs baseline: 3.8745x; 1.1098x over previous
//
#include <hip/hip_runtime.h>
#include <math.h>

static constexpr int B_ = 8, N_ = 1024, C_ = 768, H_ = 12, D_ = 64;

typedef __bf16 bf16_t;
typedef bf16_t bf16x8 __attribute__((ext_vector_type(8)));
typedef bf16_t bf16x4 __attribute__((ext_vector_type(4)));
typedef short short4v __attribute__((ext_vector_type(4)));
typedef float f32x4 __attribute__((ext_vector_type(4)));

#define MFMA32(a, b, c) __builtin_amdgcn_mfma_f32_16x16x32_bf16((a), (b), (c), 0, 0, 0)
// K=16 bf16 MFMA via intrinsic (compiler handles MFMA->VALU hazards, unlike asm)
#define MFMA16(a, b, c) __builtin_amdgcn_mfma_f32_16x16x16bf16_1k( \
    __builtin_bit_cast(short4v, (a)), __builtin_bit_cast(short4v, (b)), (c), 0, 0, 0)

__device__ __forceinline__ unsigned short f2bf(float f) {
    unsigned u = __builtin_bit_cast(unsigned, f);
    u += 0x7FFFu + ((u >> 16) & 1u);
    return (unsigned short)(u >> 16);
}

__device__ __forceinline__ float bf2f(unsigned short u) {
    return __builtin_bit_cast(float, (unsigned)u << 16);
}

__device__ __forceinline__ void gload16(void* lds, const void* g) {
    __builtin_amdgcn_global_load_lds(
        (const __attribute__((address_space(1))) unsigned int*)g,
        (__attribute__((address_space(3))) unsigned int*)lds, 16, 0, 0);
}

// swizzled byte offset for [row][64 bf16] tiles (128B rows), 16B slots
__device__ __forceinline__ int swz(int row, int kslot) {
    return row * 128 + (((kslot ^ row) & 7) << 4);
}

// ---------------------------------------------------------------------------
// fp32 -> bf16 cast, 8 elems/thread
// ---------------------------------------------------------------------------
__global__ __launch_bounds__(256)
void castx_kernel(const float* __restrict__ in, unsigned short* __restrict__ out)
{
    const int i = blockIdx.x * 256 + threadIdx.x;
    const float4 a = ((const float4*)in)[2 * i];
    const float4 b = ((const float4*)in)[2 * i + 1];
    uint4 o;
    o.x = f2bf(a.x) | ((unsigned)f2bf(a.y) << 16);
    o.y = f2bf(a.z) | ((unsigned)f2bf(a.w) << 16);
    o.z = f2bf(b.x) | ((unsigned)f2bf(b.y) << 16);
    o.w = f2bf(b.z) | ((unsigned)f2bf(b.w) << 16);
    ((uint4*)out)[i] = o;
}

// ---------------------------------------------------------------------------
// transpose+cast 4 weights [768,768] fp32 -> bf16 [N][K], z-selected
// ---------------------------------------------------------------------------
__global__ __launch_bounds__(256)
void castwT4_kernel(const float* w0, const float* w1, const float* w2, const float* w3,
                    unsigned short* o0, unsigned short* o1,
                    unsigned short* o2, unsigned short* o3)
{
    const float* w; unsigned short* wT;
    switch (blockIdx.z) {
        case 0:  w = w0; wT = o0; break;
        case 1:  w = w1; wT = o1; break;
        case 2:  w = w2; wT = o2; break;
        default: w = w3; wT = o3; break;
    }
    __shared__ float T[64][65];
    const int t = threadIdx.x;
    const int k0 = blockIdx.x * 64, n0 = blockIdx.y * 64;
    const int r = t >> 2, c0 = (t & 3) * 16;
#pragma unroll
    for (int j4 = 0; j4 < 4; ++j4) {
        const float4 v = *(const float4*)(w + (size_t)(k0 + r) * 768 + n0 + c0 + j4 * 4);
        T[r][c0 + j4 * 4 + 0] = v.x; T[r][c0 + j4 * 4 + 1] = v.y;
        T[r][c0 + j4 * 4 + 2] = v.z; T[r][c0 + j4 * 4 + 3] = v.w;
    }
    __syncthreads();
    const int nn = t >> 2;
    unsigned short o[16];
#pragma unroll
    for (int j = 0; j < 16; ++j) o[j] = f2bf(T[c0 + j][nn]);
    uint4* dst = (uint4*)(wT + (size_t)(n0 + nn) * 768 + k0 + c0);
    dst[0] = *(uint4*)(o); dst[1] = *(uint4*)(o + 8);
}

// ---------------------------------------------------------------------------
// bf16 MFMA GEMM core (m97 structure): C = A[M,K] @ BT[N,K]^T (+bias)
// BM=BN=128, BK=64; 4 waves (2x2); 16x16x32 MFMA. OutT = ushort(bf16) or float.
// ---------------------------------------------------------------------------
template <typename OutT>
__device__ __forceinline__ void gemm_body(const unsigned short* __restrict__ A,
                                          const unsigned short* __restrict__ BT,
                                          const float* __restrict__ bias,
                                          OutT* __restrict__ Cmat,
                                          int Ncols, int Kdim, int row0, int col0)
{
    __shared__ char As[128 * 128];
    __shared__ char Bs[128 * 128];

    const int tid = threadIdx.x, lane = tid & 63, w = tid >> 6;
    const int wr = w >> 1, wc = w & 1;
    const int slot = lane & 7, rsub = lane >> 3;

    f32x4 acc[4][4] = {};

    for (int k0 = 0; k0 < Kdim; k0 += 64) {
#pragma unroll
        for (int c = 0; c < 4; ++c) {
            const int chunk = c * 4 + w;
            const int r = chunk * 8 + rsub;
            gload16(As + chunk * 1024, A + (size_t)(row0 + r) * Kdim + k0 + 8 * (slot ^ (r & 7)));
            gload16(Bs + chunk * 1024, BT + (size_t)(col0 + r) * Kdim + k0 + 8 * (slot ^ (r & 7)));
        }
        __syncthreads();

#pragma unroll
        for (int kk = 0; kk < 2; ++kk) {
            const int kslot = kk * 4 + (lane >> 4);
            bf16x8 af[4], bf[4];
#pragma unroll
            for (int mi = 0; mi < 4; ++mi)
                af[mi] = *(const bf16x8*)(As + swz(wr * 64 + mi * 16 + (lane & 15), kslot));
#pragma unroll
            for (int ni = 0; ni < 4; ++ni)
                bf[ni] = *(const bf16x8*)(Bs + swz(wc * 64 + ni * 16 + (lane & 15), kslot));
#pragma unroll
            for (int mi = 0; mi < 4; ++mi)
#pragma unroll
                for (int ni = 0; ni < 4; ++ni)
                    acc[mi][ni] = MFMA32(af[mi], bf[ni], acc[mi][ni]);
        }
        __syncthreads();
    }

#pragma unroll
    for (int mi = 0; mi < 4; ++mi) {
        const int row = row0 + wr * 64 + mi * 16 + ((lane >> 4) << 2);
#pragma unroll
        for (int ni = 0; ni < 4; ++ni) {
            const int col = col0 + wc * 64 + ni * 16 + (lane & 15);
            const float bv_ = bias ? bias[col] : 0.f;
#pragma unroll
            for (int r = 0; r < 4; ++r) {
                const float v = acc[mi][ni][r] + bv_;
                if constexpr (sizeof(OutT) == 2)
                    Cmat[(size_t)(row + r) * Ncols + col] = (OutT)f2bf(v);
                else
                    Cmat[(size_t)(row + r) * Ncols + col] = v;
            }
        }
    }
}

// merged QKV projection: grid (M/128, 18); y selects q/k/v and col-tile
__global__ __launch_bounds__(256)
void gemm_qkv(const unsigned short* __restrict__ xb,
              const unsigned short* __restrict__ wqT, const unsigned short* __restrict__ wkT,
              const unsigned short* __restrict__ wvT, const float* __restrict__ bv,
              unsigned short* __restrict__ q_lin, unsigned short* __restrict__ k_lin,
              unsigned short* __restrict__ v_lin)
{
    const int by = blockIdx.y, sel = by / 6, colt = by % 6;
    const unsigned short* BT; unsigned short* dst; const float* bias = nullptr;
    if (sel == 0)      { BT = wqT; dst = q_lin; }
    else if (sel == 1) { BT = wkT; dst = k_lin; }
    else               { BT = wvT; dst = v_lin; bias = bv; }
    gemm_body<unsigned short>(xb, BT, bias, dst, C_, C_, blockIdx.x * 128, colt * 128);
}

__global__ __launch_bounds__(256)
void gemm_proj(const unsigned short* __restrict__ A, const unsigned short* __restrict__ BT,
               const float* __restrict__ bias, float* __restrict__ Cmat)
{
    gemm_body<float>(A, BT, bias, Cmat, C_, C_, blockIdx.x * 128, blockIdx.y * 128);
}

// ---------------------------------------------------------------------------
// q/k depthwise causal conv over BATCH axis; bf16 in [B,N,C] -> bf16 [BH,N,64]
// ---------------------------------------------------------------------------
__global__ __launch_bounds__(256)
void dwconv_qk(const unsigned short* __restrict__ qlin, const unsigned short* __restrict__ klin,
               const float* __restrict__ cq_w, const float* __restrict__ cq_b,
               const float* __restrict__ ck_w, const float* __restrict__ ck_b,
               unsigned short* __restrict__ qc, unsigned short* __restrict__ kc)
{
    const unsigned short* lin; const float* w; const float* bias;
    unsigned short* out;
    if (blockIdx.y == 0) { lin = qlin; w = cq_w; bias = cq_b; out = qc; }
    else                 { lin = klin; w = ck_w; bias = ck_b; out = kc; }

    const int i = blockIdx.x * 256 + threadIdx.x;
    const int c8 = i % (C_ / 8);
    const int n  = (i / (C_ / 8)) % N_;
    const int b  = i / ((C_ / 8) * N_);
    const int c  = c8 * 8;

    const uint4 z4 = make_uint4(0, 0, 0, 0);
    const uint4 x0 = (b >= 2) ? *(const uint4*)(lin + ((size_t)(b - 2) * N_ + n) * C_ + c) : z4;
    const uint4 x1 = (b >= 1) ? *(const uint4*)(lin + ((size_t)(b - 1) * N_ + n) * C_ + c) : z4;
    const uint4 x2 = *(const uint4*)(lin + ((size_t)b * N_ + n) * C_ + c);
    const unsigned short* u0 = (const unsigned short*)&x0;
    const unsigned short* u1 = (const unsigned short*)&x1;
    const unsigned short* u2 = (const unsigned short*)&x2;

    unsigned short y[8];
#pragma unroll
    for (int j = 0; j < 8; ++j) {
        const float v = w[(c + j) * 3 + 0] * bf2f(u0[j]) +
                        w[(c + j) * 3 + 1] * bf2f(u1[j]) +
                        w[(c + j) * 3 + 2] * bf2f(u2[j]) + bias[c + j];
        y[j] = f2bf(v);
    }
    const int h = c8 >> 3, d0 = (c8 & 7) * 8;
    *(uint4*)(out + (((size_t)b * H_ + h) * N_ + n) * 64 + d0) = *(uint4*)y;
}

// ---------------------------------------------------------------------------
// v path: conv over batch + transpose, bf16 [B,N,C] -> vt [BH,64,N]
// ---------------------------------------------------------------------------
__global__ __launch_bounds__(256)
void conv_v_transpose(const unsigned short* __restrict__ vlin, const float* __restrict__ w,
                      const float* __restrict__ bias, unsigned short* __restrict__ vt)
{
    __shared__ unsigned short T[64][72];
    const int t = threadIdx.x;
    const int n0 = blockIdx.x * 64, bh = blockIdx.y;
    const int b = bh / H_, h = bh % H_;
    const int r = t >> 2, c0 = (t & 3) * 16;
    const int cbase = h * 64 + c0;

    float acc[16];
#pragma unroll
    for (int i = 0; i < 16; ++i) acc[i] = bias[cbase + i];
#pragma unroll
    for (int j = 0; j < 3; ++j) {
        const int bb = b - 2 + j;
        if (bb < 0) continue;
        const unsigned short* src = vlin + ((size_t)bb * N_ + n0 + r) * C_ + cbase;
        const uint4 va = *(const uint4*)src;
        const uint4 vb2 = *(const uint4*)(src + 8);
        const unsigned short* u = (const unsigned short*)&va;
        const unsigned short* u2 = (const unsigned short*)&vb2;
#pragma unroll
        for (int i = 0; i < 8; ++i)  acc[i]     += w[(cbase + i) * 3 + j] * bf2f(u[i]);
#pragma unroll
        for (int i = 0; i < 8; ++i)  acc[8 + i] += w[(cbase + 8 + i) * 3 + j] * bf2f(u2[i]);
    }
    unsigned short tmp[16];
#pragma unroll
    for (int i = 0; i < 16; ++i) tmp[i] = f2bf(acc[i]);
    *(uint4*)&T[r][c0] = *(uint4*)tmp;
    *(uint4*)&T[r][c0 + 8] = *(uint4*)(tmp + 8);
    __syncthreads();

    const int d = t >> 2;
    unsigned short o[16];
#pragma unroll
    for (int i = 0; i < 16; ++i) o[i] = T[c0 + i][d];
    uint4* dst = (uint4*)(vt + ((size_t)bh * 64 + d) * N_ + n0 + c0);
    dst[0] = *(uint4*)o; dst[1] = *(uint4*)(o + 8);
}

// ---------------------------------------------------------------------------
// Swapped-operand MFMA flash attention (intrinsic-only).
// Q,K: [BH,N,64] bf16; Vt: [BH,64,N] bf16; O: [B,N,C] bf16.
// S^T = mfma32(K, Q): lane (g,q) holds S[q][ni*16+4g+rg] -> in-lane softmax,
// only 2 shfl per reduce. PV via mfma_f32_16x16x16bf16_1k: P fragment is
// lane-local (S D-layout == K=16 B-fragment layout); V^T from swizzled LDS.
// O accumulated transposed. Grid: 768 blocks, XCD-bijective remap.
// ---------------------------------------------------------------------------
__global__ __launch_bounds__(256)
void attn_mfma(const unsigned short* __restrict__ Qg, const unsigned short* __restrict__ Kg,
               const unsigned short* __restrict__ Vtg, unsigned short* __restrict__ Og)
{
    __shared__ char Kb[2][8192];
    __shared__ char Vb[2][8192];

    const int tid = threadIdx.x, lane = tid & 63, w = tid >> 6;
    const int g = lane >> 4, q = lane & 15;
    const int slot = lane & 7, rsub = lane >> 3;

    const int id = blockIdx.x;
    const int bh = (id & 7) * 12 + ((id >> 3) % 12);   // all 8 q-blocks of a head -> same XCD
    const int q0 = (id / 96) * 128;
    const int b = bh / H_, h = bh % H_;

    const unsigned short* Qp = Qg + (size_t)bh * N_ * 64;
    const unsigned short* Kp = Kg + (size_t)bh * N_ * 64;
    const unsigned short* Vp = Vtg + (size_t)bh * 64 * N_;

    // Q fragments straight to regs: lane holds Q[q0+w*32+mi*16+q][kk*32+g*8..+8]
    bf16x8 qf[2][2];
#pragma unroll
    for (int mi = 0; mi < 2; ++mi)
#pragma unroll
        for (int kk = 0; kk < 2; ++kk)
            qf[mi][kk] = *(const bf16x8*)(Qp + (size_t)(q0 + w * 32 + mi * 16 + q) * 64 + kk * 32 + g * 8);

    // stage K,V tile 0
#pragma unroll
    for (int c = 0; c < 2; ++c) {
        const int chunk = c * 4 + w, r = chunk * 8 + rsub;
        gload16(Kb[0] + chunk * 1024, Kp + (size_t)r * 64 + 8 * (slot ^ (r & 7)));
        gload16(Vb[0] + chunk * 1024, Vp + (size_t)r * N_ + 8 * (slot ^ (r & 7)));
    }
    __syncthreads();

    f32x4 o[2][4] = {};
    float mrun[2] = {0.f, 0.f}, lrun[2] = {0.f, 0.f};
    const float cs = 0.18033688011112042f;   // 0.125 * log2(e)

    int buf = 0;
    for (int kt = 0; kt < N_ / 64; ++kt) {
        if (kt < N_ / 64 - 1) {
            const int nb = buf ^ 1;
#pragma unroll
            for (int c = 0; c < 2; ++c) {
                const int chunk = c * 4 + w, r = chunk * 8 + rsub;
                gload16(Kb[nb] + chunk * 1024, Kp + (size_t)((kt + 1) * 64 + r) * 64 + 8 * (slot ^ (r & 7)));
                gload16(Vb[nb] + chunk * 1024, Vp + (size_t)r * N_ + (kt + 1) * 64 + 8 * (slot ^ (r & 7)));
            }
        }

        // ---- S^T = K·Q^T: D rows = kv, cols = q ----
        f32x4 s[2][4] = {};
#pragma unroll
        for (int kk = 0; kk < 2; ++kk) {
            const int kslot = kk * 4 + g;
            bf16x8 kf[4];
#pragma unroll
            for (int ni = 0; ni < 4; ++ni)
                kf[ni] = *(const bf16x8*)(Kb[buf] + swz(ni * 16 + q, kslot));
#pragma unroll
            for (int mi = 0; mi < 2; ++mi)
#pragma unroll
                for (int ni = 0; ni < 4; ++ni)
                    s[mi][ni] = MFMA32(kf[ni], qf[mi][kk], s[mi][ni]);
        }

        // ---- in-lane softmax (base-2), defer-max; 2 shfl per reduce ----
        bf16x4 pf[2][4];
#pragma unroll
        for (int mi = 0; mi < 2; ++mi) {
            float t[4][4];
#pragma unroll
            for (int ni = 0; ni < 4; ++ni)
#pragma unroll
                for (int rg = 0; rg < 4; ++rg) t[ni][rg] = s[mi][ni][rg] * cs;
            float m0 = t[0][0];
#pragma unroll
            for (int ni = 0; ni < 4; ++ni)
#pragma unroll
                for (int rg = 0; rg < 4; ++rg) m0 = fmaxf(m0, t[ni][rg]);
            m0 = fmaxf(m0, __shfl_xor(m0, 16));
            m0 = fmaxf(m0, __shfl_xor(m0, 32));
            if (__any(m0 > mrun[mi] + 8.f)) {
                const float mnew = fmaxf(mrun[mi], m0);
                const float f = exp2f(mrun[mi] - mnew);
                lrun[mi] *= f;
#pragma unroll
                for (int nd = 0; nd < 4; ++nd) o[mi][nd] *= f;
                mrun[mi] = mnew;
            }
            float sum = 0.f;
#pragma unroll
            for (int ni = 0; ni < 4; ++ni) {
                const float p0 = exp2f(t[ni][0] - mrun[mi]);
                const float p1 = exp2f(t[ni][1] - mrun[mi]);
                const float p2 = exp2f(t[ni][2] - mrun[mi]);
                const float p3 = exp2f(t[ni][3] - mrun[mi]);
                sum += (p0 + p1) + (p2 + p3);
                bf16x4 pk;
                pk[0] = (bf16_t)p0; pk[1] = (bf16_t)p1; pk[2] = (bf16_t)p2; pk[3] = (bf16_t)p3;
                pf[mi][ni] = pk;
            }
            sum += __shfl_xor(sum, 16);
            sum += __shfl_xor(sum, 32);
            lrun[mi] += sum;
        }

        // ---- O^T += V^T·P^T (K=16 MFMA, operands lane-local) ----
#pragma unroll
        for (int ni = 0; ni < 4; ++ni) {
            bf16x4 vf[4];
#pragma unroll
            for (int nd = 0; nd < 4; ++nd) {
                const int d = nd * 16 + q;
                vf[nd] = *(const bf16x4*)(Vb[buf] + d * 128 +
                          ((((2 * ni + (g >> 1)) ^ (d & 7))) << 4) + 8 * (g & 1));
            }
#pragma unroll
            for (int mi = 0; mi < 2; ++mi)
#pragma unroll
                for (int nd = 0; nd < 4; ++nd)
                    o[mi][nd] = MFMA16(vf[nd], pf[mi][ni], o[mi][nd]);
        }

        __syncthreads();
        buf ^= 1;
    }

    // epilogue: lane holds O^T[nd*16+4g+rg][q] -> Og[b, qrow, h*64 + d]
#pragma unroll
    for (int mi = 0; mi < 2; ++mi) {
        const float inv = 1.0f / lrun[mi];
        const int qrow = q0 + w * 32 + mi * 16 + q;
        unsigned short* orow = Og + ((size_t)b * N_ + qrow) * C_ + h * D_;
#pragma unroll
        for (int nd = 0; nd < 4; ++nd) {
            unsigned short pk[4];
#pragma unroll
            for (int rg = 0; rg < 4; ++rg) pk[rg] = f2bf(o[mi][nd][rg] * inv);
            *(uint2*)(orow + nd * 16 + 4 * g) = *(uint2*)pk;
        }
    }
}

// ---------------------------------------------------------------------------
extern "C" void kernel_launch(void* const* d_in, const int* in_sizes, int n_in,
                              void* d_out, int out_size, void* d_ws, size_t ws_size,
                              hipStream_t stream)
{
    (void)in_sizes; (void)n_in; (void)out_size; (void)ws_size;
    const float* x    = (const float*)d_in[0];
    const float* wq   = (const float*)d_in[1];
    const float* wk   = (const float*)d_in[2];
    const float* wv   = (const float*)d_in[3];
    const float* bv   = (const float*)d_in[4];
    const float* cq_w = (const float*)d_in[5];
    const float* cq_b = (const float*)d_in[6];
    const float* ck_w = (const float*)d_in[7];
    const float* ck_b = (const float*)d_in[8];
    const float* cv_w = (const float*)d_in[9];
    const float* cv_b = (const float*)d_in[10];
    const float* wo   = (const float*)d_in[11];
    const float* bo   = (const float*)d_in[12];
    float* out = (float*)d_out;

    char* wsb = (char*)d_ws;
    const size_t T  = (size_t)B_ * N_ * C_;       // 6,291,456 elems
    const size_t WB = (size_t)2 * 589824;         // one bf16 768x768
    unsigned short* xb  = (unsigned short*)wsb;                      // 2T B
    unsigned short* wqT = (unsigned short*)(wsb + 2 * T);
    unsigned short* wkT = wqT + 589824;
    unsigned short* wvT = wkT + 589824;
    unsigned short* woT = wvT + 589824;
    char* p = wsb + 2 * T + 4 * WB;
    unsigned short* q_lin = (unsigned short*)p;          p += 2 * T;
    unsigned short* k_lin = (unsigned short*)p;          p += 2 * T;
    unsigned short* v_lin = (unsigned short*)p;          p += 2 * T;
    unsigned short* qc    = (unsigned short*)p;          p += 2 * T;
    unsigned short* kc    = (unsigned short*)p;          p += 2 * T;
    unsigned short* vt    = (unsigned short*)p;          p += 2 * T;
    unsigned short* attn_out = xb;                 // xb dead after gemm_qkv

    const int M = B_ * N_;

    castx_kernel<<<dim3((int)(T / 8 / 256)), 256, 0, stream>>>(x, xb);
    castwT4_kernel<<<dim3(12, 12, 4), 256, 0, stream>>>(wq, wk, wv, wo, wqT, wkT, wvT, woT);

    gemm_qkv<<<dim3(M / 128, 18), 256, 0, stream>>>(xb, wqT, wkT, wvT, bv, q_lin, k_lin, v_lin);

    dwconv_qk<<<dim3((int)(T / 8 / 256), 2), 256, 0, stream>>>(
        q_lin, k_lin, cq_w, cq_b, ck_w, ck_b, qc, kc);
    conv_v_transpose<<<dim3(N_ / 64, B_ * H_), 256, 0, stream>>>(v_lin, cv_w, cv_b, vt);

    attn_mfma<<<dim3(768), 256, 0, stream>>>(qc, kc, vt, attn_out);

    gemm_proj<<<dim3(M / 128, C_ / 128), 256, 0, stream>>>(attn_out, woT, bo, out);
}

// Round 8
// 275.713 us; speedup vs baseline: 3.9039x; 1.0076x over previous
//
#include <hip/hip_runtime.h>
#include <math.h>

static constexpr int B_ = 8, N_ = 1024, C_ = 768, H_ = 12, D_ = 64;

typedef __bf16 bf16_t;
typedef bf16_t bf16x8 __attribute__((ext_vector_type(8)));
typedef bf16_t bf16x4 __attribute__((ext_vector_type(4)));
typedef short short4v __attribute__((ext_vector_type(4)));
typedef float f32x4 __attribute__((ext_vector_type(4)));

#define MFMA32(a, b, c) __builtin_amdgcn_mfma_f32_16x16x32_bf16((a), (b), (c), 0, 0, 0)
// K=16 bf16 MFMA via intrinsic (compiler handles MFMA->VALU hazards, unlike asm)
#define MFMA16(a, b, c) __builtin_amdgcn_mfma_f32_16x16x16bf16_1k( \
    __builtin_bit_cast(short4v, (a)), __builtin_bit_cast(short4v, (b)), (c), 0, 0, 0)

__device__ __forceinline__ unsigned short f2bf(float f) {
    unsigned u = __builtin_bit_cast(unsigned, f);
    u += 0x7FFFu + ((u >> 16) & 1u);
    return (unsigned short)(u >> 16);
}

__device__ __forceinline__ float bf2f(unsigned short u) {
    return __builtin_bit_cast(float, (unsigned)u << 16);
}

__device__ __forceinline__ void gload16(void* lds, const void* g) {
    __builtin_amdgcn_global_load_lds(
        (const __attribute__((address_space(1))) unsigned int*)g,
        (__attribute__((address_space(3))) unsigned int*)lds, 16, 0, 0);
}

// swizzled byte offset for [row][64 bf16] tiles (128B rows), 16B slots
__device__ __forceinline__ int swz(int row, int kslot) {
    return row * 128 + (((kslot ^ row) & 7) << 4);
}

// ---------------------------------------------------------------------------
// fp32 -> bf16 cast, 8 elems/thread
// ---------------------------------------------------------------------------
__global__ __launch_bounds__(256)
void castx_kernel(const float* __restrict__ in, unsigned short* __restrict__ out)
{
    const int i = blockIdx.x * 256 + threadIdx.x;
    const float4 a = ((const float4*)in)[2 * i];
    const float4 b = ((const float4*)in)[2 * i + 1];
    uint4 o;
    o.x = f2bf(a.x) | ((unsigned)f2bf(a.y) << 16);
    o.y = f2bf(a.z) | ((unsigned)f2bf(a.w) << 16);
    o.z = f2bf(b.x) | ((unsigned)f2bf(b.y) << 16);
    o.w = f2bf(b.z) | ((unsigned)f2bf(b.w) << 16);
    ((uint4*)out)[i] = o;
}

// ---------------------------------------------------------------------------
// transpose+cast 4 weights [768,768] fp32 -> bf16 [N][K], z-selected
// ---------------------------------------------------------------------------
__global__ __launch_bounds__(256)
void castwT4_kernel(const float* w0, const float* w1, const float* w2, const float* w3,
                    unsigned short* o0, unsigned short* o1,
                    unsigned short* o2, unsigned short* o3)
{
    const float* w; unsigned short* wT;
    switch (blockIdx.z) {
        case 0:  w = w0; wT = o0; break;
        case 1:  w = w1; wT = o1; break;
        case 2:  w = w2; wT = o2; break;
        default: w = w3; wT = o3; break;
    }
    __shared__ float T[64][65];
    const int t = threadIdx.x;
    const int k0 = blockIdx.x * 64, n0 = blockIdx.y * 64;
    const int r = t >> 2, c0 = (t & 3) * 16;
#pragma unroll
    for (int j4 = 0; j4 < 4; ++j4) {
        const float4 v = *(const float4*)(w + (size_t)(k0 + r) * 768 + n0 + c0 + j4 * 4);
        T[r][c0 + j4 * 4 + 0] = v.x; T[r][c0 + j4 * 4 + 1] = v.y;
        T[r][c0 + j4 * 4 + 2] = v.z; T[r][c0 + j4 * 4 + 3] = v.w;
    }
    __syncthreads();
    const int nn = t >> 2;
    unsigned short o[16];
#pragma unroll
    for (int j = 0; j < 16; ++j) o[j] = f2bf(T[c0 + j][nn]);
    uint4* dst = (uint4*)(wT + (size_t)(n0 + nn) * 768 + k0 + c0);
    dst[0] = *(uint4*)(o); dst[1] = *(uint4*)(o + 8);
}

// ---------------------------------------------------------------------------
// bf16 MFMA GEMM core (m97 structure): C = A[M,K] @ BT[N,K]^T (+bias)
// BM=BN=128, BK=64; 4 waves (2x2); 16x16x32 MFMA. OutT = ushort(bf16) or float.
// ---------------------------------------------------------------------------
template <typename OutT>
__device__ __forceinline__ void gemm_body(const unsigned short* __restrict__ A,
                                          const unsigned short* __restrict__ BT,
                                          const float* __restrict__ bias,
                                          OutT* __restrict__ Cmat,
                                          int Ncols, int Kdim, int row0, int col0)
{
    __shared__ char As[128 * 128];
    __shared__ char Bs[128 * 128];

    const int tid = threadIdx.x, lane = tid & 63, w = tid >> 6;
    const int wr = w >> 1, wc = w & 1;
    const int slot = lane & 7, rsub = lane >> 3;

    f32x4 acc[4][4] = {};

    for (int k0 = 0; k0 < Kdim; k0 += 64) {
#pragma unroll
        for (int c = 0; c < 4; ++c) {
            const int chunk = c * 4 + w;
            const int r = chunk * 8 + rsub;
            gload16(As + chunk * 1024, A + (size_t)(row0 + r) * Kdim + k0 + 8 * (slot ^ (r & 7)));
            gload16(Bs + chunk * 1024, BT + (size_t)(col0 + r) * Kdim + k0 + 8 * (slot ^ (r & 7)));
        }
        __syncthreads();

#pragma unroll
        for (int kk = 0; kk < 2; ++kk) {
            const int kslot = kk * 4 + (lane >> 4);
            bf16x8 af[4], bf[4];
#pragma unroll
            for (int mi = 0; mi < 4; ++mi)
                af[mi] = *(const bf16x8*)(As + swz(wr * 64 + mi * 16 + (lane & 15), kslot));
#pragma unroll
            for (int ni = 0; ni < 4; ++ni)
                bf[ni] = *(const bf16x8*)(Bs + swz(wc * 64 + ni * 16 + (lane & 15), kslot));
#pragma unroll
            for (int mi = 0; mi < 4; ++mi)
#pragma unroll
                for (int ni = 0; ni < 4; ++ni)
                    acc[mi][ni] = MFMA32(af[mi], bf[ni], acc[mi][ni]);
        }
        __syncthreads();
    }

#pragma unroll
    for (int mi = 0; mi < 4; ++mi) {
        const int row = row0 + wr * 64 + mi * 16 + ((lane >> 4) << 2);
#pragma unroll
        for (int ni = 0; ni < 4; ++ni) {
            const int col = col0 + wc * 64 + ni * 16 + (lane & 15);
            const float bv_ = bias ? bias[col] : 0.f;
#pragma unroll
            for (int r = 0; r < 4; ++r) {
                const float v = acc[mi][ni][r] + bv_;
                if constexpr (sizeof(OutT) == 2)
                    Cmat[(size_t)(row + r) * Ncols + col] = (OutT)f2bf(v);
                else
                    Cmat[(size_t)(row + r) * Ncols + col] = v;
            }
        }
    }
}

// merged QKV projection: grid (M/128, 18); y selects q/k/v and col-tile
__global__ __launch_bounds__(256)
void gemm_qkv(const unsigned short* __restrict__ xb,
              const unsigned short* __restrict__ wqT, const unsigned short* __restrict__ wkT,
              const unsigned short* __restrict__ wvT, const float* __restrict__ bv,
              unsigned short* __restrict__ q_lin, unsigned short* __restrict__ k_lin,
              unsigned short* __restrict__ v_lin)
{
    const int by = blockIdx.y, sel = by / 6, colt = by % 6;
    const unsigned short* BT; unsigned short* dst; const float* bias = nullptr;
    if (sel == 0)      { BT = wqT; dst = q_lin; }
    else if (sel == 1) { BT = wkT; dst = k_lin; }
    else               { BT = wvT; dst = v_lin; bias = bv; }
    gemm_body<unsigned short>(xb, BT, bias, dst, C_, C_, blockIdx.x * 128, colt * 128);
}

__global__ __launch_bounds__(256)
void gemm_proj(const unsigned short* __restrict__ A, const unsigned short* __restrict__ BT,
               const float* __restrict__ bias, float* __restrict__ Cmat)
{
    gemm_body<float>(A, BT, bias, Cmat, C_, C_, blockIdx.x * 128, blockIdx.y * 128);
}

// ---------------------------------------------------------------------------
// q/k depthwise causal conv over BATCH axis; bf16 in [B,N,C] -> bf16 [BH,N,64]
// ---------------------------------------------------------------------------
__global__ __launch_bounds__(256)
void dwconv_qk(const unsigned short* __restrict__ qlin, const unsigned short* __restrict__ klin,
               const float* __restrict__ cq_w, const float* __restrict__ cq_b,
               const float* __restrict__ ck_w, const float* __restrict__ ck_b,
               unsigned short* __restrict__ qc, unsigned short* __restrict__ kc)
{
    const unsigned short* lin; const float* w; const float* bias;
    unsigned short* out;
    if (blockIdx.y == 0) { lin = qlin; w = cq_w; bias = cq_b; out = qc; }
    else                 { lin = klin; w = ck_w; bias = ck_b; out = kc; }

    const int i = blockIdx.x * 256 + threadIdx.x;
    const int c8 = i % (C_ / 8);
    const int n  = (i / (C_ / 8)) % N_;
    const int b  = i / ((C_ / 8) * N_);
    const int c  = c8 * 8;

    const uint4 z4 = make_uint4(0, 0, 0, 0);
    const uint4 x0 = (b >= 2) ? *(const uint4*)(lin + ((size_t)(b - 2) * N_ + n) * C_ + c) : z4;
    const uint4 x1 = (b >= 1) ? *(const uint4*)(lin + ((size_t)(b - 1) * N_ + n) * C_ + c) : z4;
    const uint4 x2 = *(const uint4*)(lin + ((size_t)b * N_ + n) * C_ + c);
    const unsigned short* u0 = (const unsigned short*)&x0;
    const unsigned short* u1 = (const unsigned short*)&x1;
    const unsigned short* u2 = (const unsigned short*)&x2;

    unsigned short y[8];
#pragma unroll
    for (int j = 0; j < 8; ++j) {
        const float v = w[(c + j) * 3 + 0] * bf2f(u0[j]) +
                        w[(c + j) * 3 + 1] * bf2f(u1[j]) +
                        w[(c + j) * 3 + 2] * bf2f(u2[j]) + bias[c + j];
        y[j] = f2bf(v);
    }
    const int h = c8 >> 3, d0 = (c8 & 7) * 8;
    *(uint4*)(out + (((size_t)b * H_ + h) * N_ + n) * 64 + d0) = *(uint4*)y;
}

// ---------------------------------------------------------------------------
// v path: conv over batch + transpose, bf16 [B,N,C] -> vt [BH,64,N]
// ---------------------------------------------------------------------------
__global__ __launch_bounds__(256)
void conv_v_transpose(const unsigned short* __restrict__ vlin, const float* __restrict__ w,
                      const float* __restrict__ bias, unsigned short* __restrict__ vt)
{
    __shared__ unsigned short T[64][72];
    const int t = threadIdx.x;
    const int n0 = blockIdx.x * 64, bh = blockIdx.y;
    const int b = bh / H_, h = bh % H_;
    const int r = t >> 2, c0 = (t & 3) * 16;
    const int cbase = h * 64 + c0;

    float acc[16];
#pragma unroll
    for (int i = 0; i < 16; ++i) acc[i] = bias[cbase + i];
#pragma unroll
    for (int j = 0; j < 3; ++j) {
        const int bb = b - 2 + j;
        if (bb < 0) continue;
        const unsigned short* src = vlin + ((size_t)bb * N_ + n0 + r) * C_ + cbase;
        const uint4 va = *(const uint4*)src;
        const uint4 vb2 = *(const uint4*)(src + 8);
        const unsigned short* u = (const unsigned short*)&va;
        const unsigned short* u2 = (const unsigned short*)&vb2;
#pragma unroll
        for (int i = 0; i < 8; ++i)  acc[i]     += w[(cbase + i) * 3 + j] * bf2f(u[i]);
#pragma unroll
        for (int i = 0; i < 8; ++i)  acc[8 + i] += w[(cbase + 8 + i) * 3 + j] * bf2f(u2[i]);
    }
    unsigned short tmp[16];
#pragma unroll
    for (int i = 0; i < 16; ++i) tmp[i] = f2bf(acc[i]);
    *(uint4*)&T[r][c0] = *(uint4*)tmp;
    *(uint4*)&T[r][c0 + 8] = *(uint4*)(tmp + 8);
    __syncthreads();

    const int d = t >> 2;
    unsigned short o[16];
#pragma unroll
    for (int i = 0; i < 16; ++i) o[i] = T[c0 + i][d];
    uint4* dst = (uint4*)(vt + ((size_t)bh * 64 + d) * N_ + n0 + c0);
    dst[0] = *(uint4*)o; dst[1] = *(uint4*)(o + 8);
}

// ---------------------------------------------------------------------------
// Swapped-operand MFMA flash attention, QBLK=64 (4 waves x 16 q-rows).
// Q,K: [BH,N,64] bf16; Vt: [BH,64,N] bf16; O: [B,N,C] bf16.
// S^T = mfma32(K, Q): lane (g,q) holds S[q][ni*16+4g+rg] -> in-lane softmax.
// PV via mfma_f32_16x16x16bf16_1k (P fragment lane-local); V^T swizzled LDS.
// Grid: 1536 blocks, XCD-bijective remap (head's K/V pinned to one L2).
// ---------------------------------------------------------------------------
__global__ __launch_bounds__(256)
void attn_mfma(const unsigned short* __restrict__ Qg, const unsigned short* __restrict__ Kg,
               const unsigned short* __restrict__ Vtg, unsigned short* __restrict__ Og)
{
    __shared__ char Kb[2][8192];
    __shared__ char Vb[2][8192];

    const int tid = threadIdx.x, lane = tid & 63, w = tid >> 6;
    const int g = lane >> 4, q = lane & 15;
    const int slot = lane & 7, rsub = lane >> 3;

    const int id = blockIdx.x;
    const int bh = (id & 7) * 12 + ((id >> 3) % 12);   // all 16 q-tiles of a head -> same XCD
    const int q0 = (id / 96) * 64;
    const int b = bh / H_, h = bh % H_;

    const unsigned short* Qp = Qg + (size_t)bh * N_ * 64;
    const unsigned short* Kp = Kg + (size_t)bh * N_ * 64;
    const unsigned short* Vp = Vtg + (size_t)bh * 64 * N_;

    // Q fragments straight to regs: lane holds Q[q0+w*16+q][kk*32+g*8..+8]
    bf16x8 qf[2];
#pragma unroll
    for (int kk = 0; kk < 2; ++kk)
        qf[kk] = *(const bf16x8*)(Qp + (size_t)(q0 + w * 16 + q) * 64 + kk * 32 + g * 8);

    // stage K,V tile 0
#pragma unroll
    for (int c = 0; c < 2; ++c) {
        const int chunk = c * 4 + w, r = chunk * 8 + rsub;
        gload16(Kb[0] + chunk * 1024, Kp + (size_t)r * 64 + 8 * (slot ^ (r & 7)));
        gload16(Vb[0] + chunk * 1024, Vp + (size_t)r * N_ + 8 * (slot ^ (r & 7)));
    }
    __syncthreads();

    f32x4 o[4] = {};
    float mrun = 0.f, lrun = 0.f;
    const float cs = 0.18033688011112042f;   // 0.125 * log2(e)

    int buf = 0;
    for (int kt = 0; kt < N_ / 64; ++kt) {
        if (kt < N_ / 64 - 1) {
            const int nb = buf ^ 1;
#pragma unroll
            for (int c = 0; c < 2; ++c) {
                const int chunk = c * 4 + w, r = chunk * 8 + rsub;
                gload16(Kb[nb] + chunk * 1024, Kp + (size_t)((kt + 1) * 64 + r) * 64 + 8 * (slot ^ (r & 7)));
                gload16(Vb[nb] + chunk * 1024, Vp + (size_t)r * N_ + (kt + 1) * 64 + 8 * (slot ^ (r & 7)));
            }
        }

        // ---- S^T = K·Q^T: D rows = kv, cols = q ----
        f32x4 s[4] = {};
#pragma unroll
        for (int kk = 0; kk < 2; ++kk) {
            const int kslot = kk * 4 + g;
            bf16x8 kf[4];
#pragma unroll
            for (int ni = 0; ni < 4; ++ni)
                kf[ni] = *(const bf16x8*)(Kb[buf] + swz(ni * 16 + q, kslot));
#pragma unroll
            for (int ni = 0; ni < 4; ++ni)
                s[ni] = MFMA32(kf[ni], qf[kk], s[ni]);
        }

        // ---- in-lane softmax (base-2), defer-max; 2 shfl per reduce ----
        bf16x4 pf[4];
        {
            float t[4][4];
#pragma unroll
            for (int ni = 0; ni < 4; ++ni)
#pragma unroll
                for (int rg = 0; rg < 4; ++rg) t[ni][rg] = s[ni][rg] * cs;
            float m0 = t[0][0];
#pragma unroll
            for (int ni = 0; ni < 4; ++ni)
#pragma unroll
                for (int rg = 0; rg < 4; ++rg) m0 = fmaxf(m0, t[ni][rg]);
            m0 = fmaxf(m0, __shfl_xor(m0, 16));
            m0 = fmaxf(m0, __shfl_xor(m0, 32));
            if (__any(m0 > mrun + 8.f)) {
                const float mnew = fmaxf(mrun, m0);
                const float f = exp2f(mrun - mnew);
                lrun *= f;
#pragma unroll
                for (int nd = 0; nd < 4; ++nd) o[nd] *= f;
                mrun = mnew;
            }
            float sum = 0.f;
#pragma unroll
            for (int ni = 0; ni < 4; ++ni) {
                const float p0 = exp2f(t[ni][0] - mrun);
                const float p1 = exp2f(t[ni][1] - mrun);
                const float p2 = exp2f(t[ni][2] - mrun);
                const float p3 = exp2f(t[ni][3] - mrun);
                sum += (p0 + p1) + (p2 + p3);
                bf16x4 pk;
                pk[0] = (bf16_t)p0; pk[1] = (bf16_t)p1; pk[2] = (bf16_t)p2; pk[3] = (bf16_t)p3;
                pf[ni] = pk;
            }
            sum += __shfl_xor(sum, 16);
            sum += __shfl_xor(sum, 32);
            lrun += sum;
        }

        // ---- O^T += V^T·P^T (K=16 MFMA, operands lane-local) ----
#pragma unroll
        for (int ni = 0; ni < 4; ++ni) {
            bf16x4 vf[4];
#pragma unroll
            for (int nd = 0; nd < 4; ++nd) {
                const int d = nd * 16 + q;
                vf[nd] = *(const bf16x4*)(Vb[buf] + d * 128 +
                          ((((2 * ni + (g >> 1)) ^ (d & 7))) << 4) + 8 * (g & 1));
            }
#pragma unroll
            for (int nd = 0; nd < 4; ++nd)
                o[nd] = MFMA16(vf[nd], pf[ni], o[nd]);
        }

        __syncthreads();
        buf ^= 1;
    }

    // epilogue: lane holds O^T[nd*16+4g+rg][q] -> Og[b, qrow, h*64 + d]
    {
        const float inv = 1.0f / lrun;
        const int qrow = q0 + w * 16 + q;
        unsigned short* orow = Og + ((size_t)b * N_ + qrow) * C_ + h * D_;
#pragma unroll
        for (int nd = 0; nd < 4; ++nd) {
            unsigned short pk[4];
#pragma unroll
            for (int rg = 0; rg < 4; ++rg) pk[rg] = f2bf(o[nd][rg] * inv);
            *(uint2*)(orow + nd * 16 + 4 * g) = *(uint2*)pk;
        }
    }
}

// ---------------------------------------------------------------------------
extern "C" void kernel_launch(void* const* d_in, const int* in_sizes, int n_in,
                              void* d_out, int out_size, void* d_ws, size_t ws_size,
                              hipStream_t stream)
{
    (void)in_sizes; (void)n_in; (void)out_size; (void)ws_size;
    const float* x    = (const float*)d_in[0];
    const float* wq   = (const float*)d_in[1];
    const float* wk   = (const float*)d_in[2];
    const float* wv   = (const float*)d_in[3];
    const float* bv   = (const float*)d_in[4];
    const float* cq_w = (const float*)d_in[5];
    const float* cq_b = (const float*)d_in[6];
    const float* ck_w = (const float*)d_in[7];
    const float* ck_b = (const float*)d_in[8];
    const float* cv_w = (const float*)d_in[9];
    const float* cv_b = (const float*)d_in[10];
    const float* wo   = (const float*)d_in[11];
    const float* bo   = (const float*)d_in[12];
    float* out = (float*)d_out;

    char* wsb = (char*)d_ws;
    const size_t T  = (size_t)B_ * N_ * C_;       // 6,291,456 elems
    const size_t WB = (size_t)2 * 589824;         // one bf16 768x768
    unsigned short* xb  = (unsigned short*)wsb;                      // 2T B
    unsigned short* wqT = (unsigned short*)(wsb + 2 * T);
    unsigned short* wkT = wqT + 589824;
    unsigned short* wvT = wkT + 589824;
    unsigned short* woT = wvT + 589824;
    char* p = wsb + 2 * T + 4 * WB;
    unsigned short* q_lin = (unsigned short*)p;          p += 2 * T;
    unsigned short* k_lin = (unsigned short*)p;          p += 2 * T;
    unsigned short* v_lin = (unsigned short*)p;          p += 2 * T;
    unsigned short* qc    = (unsigned short*)p;          p += 2 * T;
    unsigned short* kc    = (unsigned short*)p;          p += 2 * T;
    unsigned short* vt    = (unsigned short*)p;          p += 2 * T;
    unsigned short* attn_out = xb;                 // xb dead after gemm_qkv

    const int M = B_ * N_;

    castx_kernel<<<dim3((int)(T / 8 / 256)), 256, 0, stream>>>(x, xb);
    castwT4_kernel<<<dim3(12, 12, 4), 256, 0, stream>>>(wq, wk, wv, wo, wqT, wkT, wvT, woT);

    gemm_qkv<<<dim3(M / 128, 18), 256, 0, stream>>>(xb, wqT, wkT, wvT, bv, q_lin, k_lin, v_lin);

    dwconv_qk<<<dim3((int)(T / 8 / 256), 2), 256, 0, stream>>>(
        q_lin, k_lin, cq_w, cq_b, ck_w, ck_b, qc, kc);
    conv_v_transpose<<<dim3(N_ / 64, B_ * H_), 256, 0, stream>>>(v_lin, cv_w, cv_b, vt);

    attn_mfma<<<dim3(1536), 256, 0, stream>>>(qc, kc, vt, attn_out);

    gemm_proj<<<dim3(M / 128, C_ / 128), 256, 0, stream>>>(attn_out, woT, bo, out);
}

// Round 9
// 263.398 us; speedup vs baseline: 4.0864x; 1.0468x over previous
//
#include <hip/hip_runtime.h>
#include <math.h>

static constexpr int B_ = 8, N_ = 1024, C_ = 768, H_ = 12, D_ = 64;

typedef __bf16 bf16_t;
typedef bf16_t bf16x8 __attribute__((ext_vector_type(8)));
typedef bf16_t bf16x4 __attribute__((ext_vector_type(4)));
typedef short short4v __attribute__((ext_vector_type(4)));
typedef float f32x4 __attribute__((ext_vector_type(4)));

#define MFMA32(a, b, c) __builtin_amdgcn_mfma_f32_16x16x32_bf16((a), (b), (c), 0, 0, 0)
// K=16 bf16 MFMA via intrinsic (compiler handles MFMA->VALU hazards, unlike asm)
#define MFMA16(a, b, c) __builtin_amdgcn_mfma_f32_16x16x16bf16_1k( \
    __builtin_bit_cast(short4v, (a)), __builtin_bit_cast(short4v, (b)), (c), 0, 0, 0)

__device__ __forceinline__ unsigned short f2bf(float f) {
    unsigned u = __builtin_bit_cast(unsigned, f);
    u += 0x7FFFu + ((u >> 16) & 1u);
    return (unsigned short)(u >> 16);
}

__device__ __forceinline__ float bf2f(unsigned short u) {
    return __builtin_bit_cast(float, (unsigned)u << 16);
}

__device__ __forceinline__ void gload16(void* lds, const void* g) {
    __builtin_amdgcn_global_load_lds(
        (const __attribute__((address_space(1))) unsigned int*)g,
        (__attribute__((address_space(3))) unsigned int*)lds, 16, 0, 0);
}

// swizzled byte offset for [row][64 bf16] tiles (128B rows), 16B slots
__device__ __forceinline__ int swz(int row, int kslot) {
    return row * 128 + (((kslot ^ row) & 7) << 4);
}

// ---------------------------------------------------------------------------
// fp32 -> bf16 cast, 8 elems/thread
// ---------------------------------------------------------------------------
__global__ __launch_bounds__(256)
void castx_kernel(const float* __restrict__ in, unsigned short* __restrict__ out)
{
    const int i = blockIdx.x * 256 + threadIdx.x;
    const float4 a = ((const float4*)in)[2 * i];
    const float4 b = ((const float4*)in)[2 * i + 1];
    uint4 o;
    o.x = f2bf(a.x) | ((unsigned)f2bf(a.y) << 16);
    o.y = f2bf(a.z) | ((unsigned)f2bf(a.w) << 16);
    o.z = f2bf(b.x) | ((unsigned)f2bf(b.y) << 16);
    o.w = f2bf(b.z) | ((unsigned)f2bf(b.w) << 16);
    ((uint4*)out)[i] = o;
}

// ---------------------------------------------------------------------------
// transpose+cast 4 weights [768,768] fp32 -> bf16 [N][K], z-selected
// ---------------------------------------------------------------------------
__global__ __launch_bounds__(256)
void castwT4_kernel(const float* w0, const float* w1, const float* w2, const float* w3,
                    unsigned short* o0, unsigned short* o1,
                    unsigned short* o2, unsigned short* o3)
{
    const float* w; unsigned short* wT;
    switch (blockIdx.z) {
        case 0:  w = w0; wT = o0; break;
        case 1:  w = w1; wT = o1; break;
        case 2:  w = w2; wT = o2; break;
        default: w = w3; wT = o3; break;
    }
    __shared__ float T[64][65];
    const int t = threadIdx.x;
    const int k0 = blockIdx.x * 64, n0 = blockIdx.y * 64;
    const int r = t >> 2, c0 = (t & 3) * 16;
#pragma unroll
    for (int j4 = 0; j4 < 4; ++j4) {
        const float4 v = *(const float4*)(w + (size_t)(k0 + r) * 768 + n0 + c0 + j4 * 4);
        T[r][c0 + j4 * 4 + 0] = v.x; T[r][c0 + j4 * 4 + 1] = v.y;
        T[r][c0 + j4 * 4 + 2] = v.z; T[r][c0 + j4 * 4 + 3] = v.w;
    }
    __syncthreads();
    const int nn = t >> 2;
    unsigned short o[16];
#pragma unroll
    for (int j = 0; j < 16; ++j) o[j] = f2bf(T[c0 + j][nn]);
    uint4* dst = (uint4*)(wT + (size_t)(n0 + nn) * 768 + k0 + c0);
    dst[0] = *(uint4*)(o); dst[1] = *(uint4*)(o + 8);
}

// ---------------------------------------------------------------------------
// bf16 MFMA GEMM core (m97 structure): C = A[M,K] @ BT[N,K]^T (+bias)
// BM=BN=128, BK=64; 4 waves (2x2); 16x16x32 MFMA. OutT = ushort(bf16) or float.
// ---------------------------------------------------------------------------
template <typename OutT>
__device__ __forceinline__ void gemm_body(const unsigned short* __restrict__ A,
                                          const unsigned short* __restrict__ BT,
                                          const float* __restrict__ bias,
                                          OutT* __restrict__ Cmat,
                                          int Ncols, int Kdim, int row0, int col0)
{
    __shared__ char As[128 * 128];
    __shared__ char Bs[128 * 128];

    const int tid = threadIdx.x, lane = tid & 63, w = tid >> 6;
    const int wr = w >> 1, wc = w & 1;
    const int slot = lane & 7, rsub = lane >> 3;

    f32x4 acc[4][4] = {};

    for (int k0 = 0; k0 < Kdim; k0 += 64) {
#pragma unroll
        for (int c = 0; c < 4; ++c) {
            const int chunk = c * 4 + w;
            const int r = chunk * 8 + rsub;
            gload16(As + chunk * 1024, A + (size_t)(row0 + r) * Kdim + k0 + 8 * (slot ^ (r & 7)));
            gload16(Bs + chunk * 1024, BT + (size_t)(col0 + r) * Kdim + k0 + 8 * (slot ^ (r & 7)));
        }
        __syncthreads();

#pragma unroll
        for (int kk = 0; kk < 2; ++kk) {
            const int kslot = kk * 4 + (lane >> 4);
            bf16x8 af[4], bf[4];
#pragma unroll
            for (int mi = 0; mi < 4; ++mi)
                af[mi] = *(const bf16x8*)(As + swz(wr * 64 + mi * 16 + (lane & 15), kslot));
#pragma unroll
            for (int ni = 0; ni < 4; ++ni)
                bf[ni] = *(const bf16x8*)(Bs + swz(wc * 64 + ni * 16 + (lane & 15), kslot));
            __builtin_amdgcn_s_setprio(1);
#pragma unroll
            for (int mi = 0; mi < 4; ++mi)
#pragma unroll
                for (int ni = 0; ni < 4; ++ni)
                    acc[mi][ni] = MFMA32(af[mi], bf[ni], acc[mi][ni]);
            __builtin_amdgcn_s_setprio(0);
        }
        __syncthreads();
    }

#pragma unroll
    for (int mi = 0; mi < 4; ++mi) {
        const int row = row0 + wr * 64 + mi * 16 + ((lane >> 4) << 2);
#pragma unroll
        for (int ni = 0; ni < 4; ++ni) {
            const int col = col0 + wc * 64 + ni * 16 + (lane & 15);
            const float bv_ = bias ? bias[col] : 0.f;
#pragma unroll
            for (int r = 0; r < 4; ++r) {
                const float v = acc[mi][ni][r] + bv_;
                if constexpr (sizeof(OutT) == 2)
                    Cmat[(size_t)(row + r) * Ncols + col] = (OutT)f2bf(v);
                else
                    Cmat[(size_t)(row + r) * Ncols + col] = v;
            }
        }
    }
}

// merged QKV projection: 1-D grid 1152, XCD-bijective decode so all 18
// (sel,colt) blocks sharing one A row-tile land on the same XCD's L2.
__global__ __launch_bounds__(256)
void gemm_qkv(const unsigned short* __restrict__ xb,
              const unsigned short* __restrict__ wqT, const unsigned short* __restrict__ wkT,
              const unsigned short* __restrict__ wvT, const float* __restrict__ bv,
              unsigned short* __restrict__ q_lin, unsigned short* __restrict__ k_lin,
              unsigned short* __restrict__ v_lin)
{
    const int id = blockIdx.x;
    const int j = id >> 3;
    const int bx = (id & 7) * 8 + j / 18;    // row-tile; 8 tiles per XCD
    const int by = j % 18;
    const int sel = by / 6, colt = by % 6;
    const unsigned short* BT; unsigned short* dst; const float* bias = nullptr;
    if (sel == 0)      { BT = wqT; dst = q_lin; }
    else if (sel == 1) { BT = wkT; dst = k_lin; }
    else               { BT = wvT; dst = v_lin; bias = bv; }
    gemm_body<unsigned short>(xb, BT, bias, dst, C_, C_, bx * 128, colt * 128);
}

// projection: 1-D grid 384, same XCD decode (6 col-tiles per row-tile)
__global__ __launch_bounds__(256)
void gemm_proj(const unsigned short* __restrict__ A, const unsigned short* __restrict__ BT,
               const float* __restrict__ bias, float* __restrict__ Cmat)
{
    const int id = blockIdx.x;
    const int j = id >> 3;
    const int bx = (id & 7) * 8 + j / 6;
    const int by = j % 6;
    gemm_body<float>(A, BT, bias, Cmat, C_, C_, bx * 128, by * 128);
}

// ---------------------------------------------------------------------------
// q/k depthwise causal conv over BATCH axis; bf16 in [B,N,C] -> bf16 [BH,N,64]
// ---------------------------------------------------------------------------
__global__ __launch_bounds__(256)
void dwconv_qk(const unsigned short* __restrict__ qlin, const unsigned short* __restrict__ klin,
               const float* __restrict__ cq_w, const float* __restrict__ cq_b,
               const float* __restrict__ ck_w, const float* __restrict__ ck_b,
               unsigned short* __restrict__ qc, unsigned short* __restrict__ kc)
{
    const unsigned short* lin; const float* w; const float* bias;
    unsigned short* out;
    if (blockIdx.y == 0) { lin = qlin; w = cq_w; bias = cq_b; out = qc; }
    else                 { lin = klin; w = ck_w; bias = ck_b; out = kc; }

    const int i = blockIdx.x * 256 + threadIdx.x;
    const int c8 = i % (C_ / 8);
    const int n  = (i / (C_ / 8)) % N_;
    const int b  = i / ((C_ / 8) * N_);
    const int c  = c8 * 8;

    const uint4 z4 = make_uint4(0, 0, 0, 0);
    const uint4 x0 = (b >= 2) ? *(const uint4*)(lin + ((size_t)(b - 2) * N_ + n) * C_ + c) : z4;
    const uint4 x1 = (b >= 1) ? *(const uint4*)(lin + ((size_t)(b - 1) * N_ + n) * C_ + c) : z4;
    const uint4 x2 = *(const uint4*)(lin + ((size_t)b * N_ + n) * C_ + c);
    const unsigned short* u0 = (const unsigned short*)&x0;
    const unsigned short* u1 = (const unsigned short*)&x1;
    const unsigned short* u2 = (const unsigned short*)&x2;

    unsigned short y[8];
#pragma unroll
    for (int j = 0; j < 8; ++j) {
        const float v = w[(c + j) * 3 + 0] * bf2f(u0[j]) +
                        w[(c + j) * 3 + 1] * bf2f(u1[j]) +
                        w[(c + j) * 3 + 2] * bf2f(u2[j]) + bias[c + j];
        y[j] = f2bf(v);
    }
    const int h = c8 >> 3, d0 = (c8 & 7) * 8;
    *(uint4*)(out + (((size_t)b * H_ + h) * N_ + n) * 64 + d0) = *(uint4*)y;
}

// ---------------------------------------------------------------------------
// v path: conv over batch + transpose, bf16 [B,N,C] -> vt [BH,64,N]
// ---------------------------------------------------------------------------
__global__ __launch_bounds__(256)
void conv_v_transpose(const unsigned short* __restrict__ vlin, const float* __restrict__ w,
                      const float* __restrict__ bias, unsigned short* __restrict__ vt)
{
    __shared__ unsigned short T[64][72];
    const int t = threadIdx.x;
    const int n0 = blockIdx.x * 64, bh = blockIdx.y;
    const int b = bh / H_, h = bh % H_;
    const int r = t >> 2, c0 = (t & 3) * 16;
    const int cbase = h * 64 + c0;

    float acc[16];
#pragma unroll
    for (int i = 0; i < 16; ++i) acc[i] = bias[cbase + i];
#pragma unroll
    for (int j = 0; j < 3; ++j) {
        const int bb = b - 2 + j;
        if (bb < 0) continue;
        const unsigned short* src = vlin + ((size_t)bb * N_ + n0 + r) * C_ + cbase;
        const uint4 va = *(const uint4*)src;
        const uint4 vb2 = *(const uint4*)(src + 8);
        const unsigned short* u = (const unsigned short*)&va;
        const unsigned short* u2 = (const unsigned short*)&vb2;
#pragma unroll
        for (int i = 0; i < 8; ++i)  acc[i]     += w[(cbase + i) * 3 + j] * bf2f(u[i]);
#pragma unroll
        for (int i = 0; i < 8; ++i)  acc[8 + i] += w[(cbase + 8 + i) * 3 + j] * bf2f(u2[i]);
    }
    unsigned short tmp[16];
#pragma unroll
    for (int i = 0; i < 16; ++i) tmp[i] = f2bf(acc[i]);
    *(uint4*)&T[r][c0] = *(uint4*)tmp;
    *(uint4*)&T[r][c0 + 8] = *(uint4*)(tmp + 8);
    __syncthreads();

    const int d = t >> 2;
    unsigned short o[16];
#pragma unroll
    for (int i = 0; i < 16; ++i) o[i] = T[c0 + i][d];
    uint4* dst = (uint4*)(vt + ((size_t)bh * 64 + d) * N_ + n0 + c0);
    dst[0] = *(uint4*)o; dst[1] = *(uint4*)(o + 8);
}

// ---------------------------------------------------------------------------
// Swapped-operand MFMA flash attention, QBLK=64 (4 waves x 16 q-rows).
// Q,K: [BH,N,64] bf16; Vt: [BH,64,N] bf16; O: [B,N,C] bf16.
// S^T = mfma32(K, Q): lane (g,q) holds S[q][ni*16+4g+rg] -> in-lane softmax.
// PV via mfma_f32_16x16x16bf16_1k (P fragment lane-local); V^T swizzled LDS.
// Softmax: raw-max guard, exp2(fma(s,cs,-mrun)), per-lane lrun partial
// (cross-lane reduced once in epilogue). s_setprio around MFMA clusters.
// Grid: 1536 blocks, XCD-bijective remap (head's K/V pinned to one L2).
// ---------------------------------------------------------------------------
__global__ __launch_bounds__(256)
void attn_mfma(const unsigned short* __restrict__ Qg, const unsigned short* __restrict__ Kg,
               const unsigned short* __restrict__ Vtg, unsigned short* __restrict__ Og)
{
    __shared__ char Kb[2][8192];
    __shared__ char Vb[2][8192];

    const int tid = threadIdx.x, lane = tid & 63, w = tid >> 6;
    const int g = lane >> 4, q = lane & 15;
    const int slot = lane & 7, rsub = lane >> 3;

    const int id = blockIdx.x;
    const int bh = (id & 7) * 12 + ((id >> 3) % 12);   // all 16 q-tiles of a head -> same XCD
    const int q0 = (id / 96) * 64;
    const int b = bh / H_, h = bh % H_;

    const unsigned short* Qp = Qg + (size_t)bh * N_ * 64;
    const unsigned short* Kp = Kg + (size_t)bh * N_ * 64;
    const unsigned short* Vp = Vtg + (size_t)bh * 64 * N_;

    // Q fragments straight to regs: lane holds Q[q0+w*16+q][kk*32+g*8..+8]
    bf16x8 qf[2];
#pragma unroll
    for (int kk = 0; kk < 2; ++kk)
        qf[kk] = *(const bf16x8*)(Qp + (size_t)(q0 + w * 16 + q) * 64 + kk * 32 + g * 8);

    // stage K,V tile 0
#pragma unroll
    for (int c = 0; c < 2; ++c) {
        const int chunk = c * 4 + w, r = chunk * 8 + rsub;
        gload16(Kb[0] + chunk * 1024, Kp + (size_t)r * 64 + 8 * (slot ^ (r & 7)));
        gload16(Vb[0] + chunk * 1024, Vp + (size_t)r * N_ + 8 * (slot ^ (r & 7)));
    }
    __syncthreads();

    f32x4 o[4] = {};
    float mrun = 0.f, lrun = 0.f;       // lrun is a PER-LANE partial now
    const float cs = 0.18033688011112042f;   // 0.125 * log2(e)

    int buf = 0;
    for (int kt = 0; kt < N_ / 64; ++kt) {
        if (kt < N_ / 64 - 1) {
            const int nb = buf ^ 1;
#pragma unroll
            for (int c = 0; c < 2; ++c) {
                const int chunk = c * 4 + w, r = chunk * 8 + rsub;
                gload16(Kb[nb] + chunk * 1024, Kp + (size_t)((kt + 1) * 64 + r) * 64 + 8 * (slot ^ (r & 7)));
                gload16(Vb[nb] + chunk * 1024, Vp + (size_t)r * N_ + (kt + 1) * 64 + 8 * (slot ^ (r & 7)));
            }
        }

        // ---- S^T = K·Q^T: D rows = kv, cols = q ----
        f32x4 s[4] = {};
#pragma unroll
        for (int kk = 0; kk < 2; ++kk) {
            const int kslot = kk * 4 + g;
            bf16x8 kf[4];
#pragma unroll
            for (int ni = 0; ni < 4; ++ni)
                kf[ni] = *(const bf16x8*)(Kb[buf] + swz(ni * 16 + q, kslot));
            __builtin_amdgcn_s_setprio(1);
#pragma unroll
            for (int ni = 0; ni < 4; ++ni)
                s[ni] = MFMA32(kf[ni], qf[kk], s[ni]);
            __builtin_amdgcn_s_setprio(0);
        }

        // ---- in-lane softmax (base-2): raw max guard, fma-folded exp arg ----
        bf16x4 pf[4];
        {
            float m0 = s[0][0];
#pragma unroll
            for (int ni = 0; ni < 4; ++ni)
#pragma unroll
                for (int rg = 0; rg < 4; ++rg) m0 = fmaxf(m0, s[ni][rg]);
            m0 = fmaxf(m0, __shfl_xor(m0, 16));
            m0 = fmaxf(m0, __shfl_xor(m0, 32));
            if (__any(m0 * cs > mrun + 8.f)) {      // never fires for this data
                const float mnew = m0 * cs;
                const float f = exp2f(mrun - mnew);
                lrun *= f;
#pragma unroll
                for (int nd = 0; nd < 4; ++nd) o[nd] *= f;
                mrun = mnew;
            }
#pragma unroll
            for (int ni = 0; ni < 4; ++ni) {
                const float p0 = exp2f(fmaf(s[ni][0], cs, -mrun));
                const float p1 = exp2f(fmaf(s[ni][1], cs, -mrun));
                const float p2 = exp2f(fmaf(s[ni][2], cs, -mrun));
                const float p3 = exp2f(fmaf(s[ni][3], cs, -mrun));
                lrun += (p0 + p1) + (p2 + p3);
                bf16x4 pk;
                pk[0] = (bf16_t)p0; pk[1] = (bf16_t)p1; pk[2] = (bf16_t)p2; pk[3] = (bf16_t)p3;
                pf[ni] = pk;
            }
        }

        // ---- O^T += V^T·P^T (K=16 MFMA, operands lane-local) ----
#pragma unroll
        for (int ni = 0; ni < 4; ++ni) {
            bf16x4 vf[4];
#pragma unroll
            for (int nd = 0; nd < 4; ++nd) {
                const int d = nd * 16 + q;
                vf[nd] = *(const bf16x4*)(Vb[buf] + d * 128 +
                          ((((2 * ni + (g >> 1)) ^ (d & 7))) << 4) + 8 * (g & 1));
            }
            __builtin_amdgcn_s_setprio(1);
#pragma unroll
            for (int nd = 0; nd < 4; ++nd)
                o[nd] = MFMA16(vf[nd], pf[ni], o[nd]);
            __builtin_amdgcn_s_setprio(0);
        }

        __syncthreads();
        buf ^= 1;
    }

    // epilogue: reduce lrun across the q-group, then write O^T -> Og
    {
        lrun += __shfl_xor(lrun, 16);
        lrun += __shfl_xor(lrun, 32);
        const float inv = 1.0f / lrun;
        const int qrow = q0 + w * 16 + q;
        unsigned short* orow = Og + ((size_t)b * N_ + qrow) * C_ + h * D_;
#pragma unroll
        for (int nd = 0; nd < 4; ++nd) {
            unsigned short pk[4];
#pragma unroll
            for (int rg = 0; rg < 4; ++rg) pk[rg] = f2bf(o[nd][rg] * inv);
            *(uint2*)(orow + nd * 16 + 4 * g) = *(uint2*)pk;
        }
    }
}

// ---------------------------------------------------------------------------
extern "C" void kernel_launch(void* const* d_in, const int* in_sizes, int n_in,
                              void* d_out, int out_size, void* d_ws, size_t ws_size,
                              hipStream_t stream)
{
    (void)in_sizes; (void)n_in; (void)out_size; (void)ws_size;
    const float* x    = (const float*)d_in[0];
    const float* wq   = (const float*)d_in[1];
    const float* wk   = (const float*)d_in[2];
    const float* wv   = (const float*)d_in[3];
    const float* bv   = (const float*)d_in[4];
    const float* cq_w = (const float*)d_in[5];
    const float* cq_b = (const float*)d_in[6];
    const float* ck_w = (const float*)d_in[7];
    const float* ck_b = (const float*)d_in[8];
    const float* cv_w = (const float*)d_in[9];
    const float* cv_b = (const float*)d_in[10];
    const float* wo   = (const float*)d_in[11];
    const float* bo   = (const float*)d_in[12];
    float* out = (float*)d_out;

    char* wsb = (char*)d_ws;
    const size_t T  = (size_t)B_ * N_ * C_;       // 6,291,456 elems
    const size_t WB = (size_t)2 * 589824;         // one bf16 768x768
    unsigned short* xb  = (unsigned short*)wsb;                      // 2T B
    unsigned short* wqT = (unsigned short*)(wsb + 2 * T);
    unsigned short* wkT = wqT + 589824;
    unsigned short* wvT = wkT + 589824;
    unsigned short* woT = wvT + 589824;
    char* p = wsb + 2 * T + 4 * WB;
    unsigned short* q_lin = (unsigned short*)p;          p += 2 * T;
    unsigned short* k_lin = (unsigned short*)p;          p += 2 * T;
    unsigned short* v_lin = (unsigned short*)p;          p += 2 * T;
    unsigned short* qc    = (unsigned short*)p;          p += 2 * T;
    unsigned short* kc    = (unsigned short*)p;          p += 2 * T;
    unsigned short* vt    = (unsigned short*)p;          p += 2 * T;
    unsigned short* attn_out = xb;                 // xb dead after gemm_qkv

    const int M = B_ * N_;

    castx_kernel<<<dim3((int)(T / 8 / 256)), 256, 0, stream>>>(x, xb);
    castwT4_kernel<<<dim3(12, 12, 4), 256, 0, stream>>>(wq, wk, wv, wo, wqT, wkT, wvT, woT);

    gemm_qkv<<<dim3((M / 128) * 18), 256, 0, stream>>>(xb, wqT, wkT, wvT, bv, q_lin, k_lin, v_lin);

    dwconv_qk<<<dim3((int)(T / 8 / 256), 2), 256, 0, stream>>>(
        q_lin, k_lin, cq_w, cq_b, ck_w, ck_b, qc, kc);
    conv_v_transpose<<<dim3(N_ / 64, B_ * H_), 256, 0, stream>>>(v_lin, cv_w, cv_b, vt);

    attn_mfma<<<dim3(1536), 256, 0, stream>>>(qc, kc, vt, attn_out);

    gemm_proj<<<dim3((M / 128) * 6), 256, 0, stream>>>(attn_out, woT, bo, out);
}

// Round 10
// 261.783 us; speedup vs baseline: 4.1117x; 1.0062x over previous
//
#include <hip/hip_runtime.h>
#include <math.h>

static constexpr int B_ = 8, N_ = 1024, C_ = 768, H_ = 12, D_ = 64;

typedef __bf16 bf16_t;
typedef bf16_t bf16x8 __attribute__((ext_vector_type(8)));
typedef bf16_t bf16x4 __attribute__((ext_vector_type(4)));
typedef short short4v __attribute__((ext_vector_type(4)));
typedef float f32x4 __attribute__((ext_vector_type(4)));

#define MFMA32(a, b, c) __builtin_amdgcn_mfma_f32_16x16x32_bf16((a), (b), (c), 0, 0, 0)
// K=16 bf16 MFMA via intrinsic (compiler handles MFMA->VALU hazards, unlike asm)
#define MFMA16(a, b, c) __builtin_amdgcn_mfma_f32_16x16x16bf16_1k( \
    __builtin_bit_cast(short4v, (a)), __builtin_bit_cast(short4v, (b)), (c), 0, 0, 0)

__device__ __forceinline__ unsigned short f2bf(float f) {
    unsigned u = __builtin_bit_cast(unsigned, f);
    u += 0x7FFFu + ((u >> 16) & 1u);
    return (unsigned short)(u >> 16);
}

__device__ __forceinline__ float bf2f(unsigned short u) {
    return __builtin_bit_cast(float, (unsigned)u << 16);
}

__device__ __forceinline__ void gload16(void* lds, const void* g) {
    __builtin_amdgcn_global_load_lds(
        (const __attribute__((address_space(1))) unsigned int*)g,
        (__attribute__((address_space(3))) unsigned int*)lds, 16, 0, 0);
}

// swizzled byte offset for [row][64 bf16] tiles (128B rows), 16B slots
__device__ __forceinline__ int swz(int row, int kslot) {
    return row * 128 + (((kslot ^ row) & 7) << 4);
}

// ---------------------------------------------------------------------------
// fp32 -> bf16 cast, 8 elems/thread
// ---------------------------------------------------------------------------
__global__ __launch_bounds__(256)
void castx_kernel(const float* __restrict__ in, unsigned short* __restrict__ out)
{
    const int i = blockIdx.x * 256 + threadIdx.x;
    const float4 a = ((const float4*)in)[2 * i];
    const float4 b = ((const float4*)in)[2 * i + 1];
    uint4 o;
    o.x = f2bf(a.x) | ((unsigned)f2bf(a.y) << 16);
    o.y = f2bf(a.z) | ((unsigned)f2bf(a.w) << 16);
    o.z = f2bf(b.x) | ((unsigned)f2bf(b.y) << 16);
    o.w = f2bf(b.z) | ((unsigned)f2bf(b.w) << 16);
    ((uint4*)out)[i] = o;
}

// ---------------------------------------------------------------------------
// transpose+cast 4 weights [768,768] fp32 -> bf16 [N][K], z-selected
// ---------------------------------------------------------------------------
__global__ __launch_bounds__(256)
void castwT4_kernel(const float* w0, const float* w1, const float* w2, const float* w3,
                    unsigned short* o0, unsigned short* o1,
                    unsigned short* o2, unsigned short* o3)
{
    const float* w; unsigned short* wT;
    switch (blockIdx.z) {
        case 0:  w = w0; wT = o0; break;
        case 1:  w = w1; wT = o1; break;
        case 2:  w = w2; wT = o2; break;
        default: w = w3; wT = o3; break;
    }
    __shared__ float T[64][65];
    const int t = threadIdx.x;
    const int k0 = blockIdx.x * 64, n0 = blockIdx.y * 64;
    const int r = t >> 2, c0 = (t & 3) * 16;
#pragma unroll
    for (int j4 = 0; j4 < 4; ++j4) {
        const float4 v = *(const float4*)(w + (size_t)(k0 + r) * 768 + n0 + c0 + j4 * 4);
        T[r][c0 + j4 * 4 + 0] = v.x; T[r][c0 + j4 * 4 + 1] = v.y;
        T[r][c0 + j4 * 4 + 2] = v.z; T[r][c0 + j4 * 4 + 3] = v.w;
    }
    __syncthreads();
    const int nn = t >> 2;
    unsigned short o[16];
#pragma unroll
    for (int j = 0; j < 16; ++j) o[j] = f2bf(T[c0 + j][nn]);
    uint4* dst = (uint4*)(wT + (size_t)(n0 + nn) * 768 + k0 + c0);
    dst[0] = *(uint4*)(o); dst[1] = *(uint4*)(o + 8);
}

// ---------------------------------------------------------------------------
// bf16 MFMA GEMM core (m97 structure): C = A[M,K] @ BT[N,K]^T (+bias)
// BM=BN=128, BK=64; 4 waves (2x2); 16x16x32 MFMA. OutT = ushort(bf16) or float.
// ---------------------------------------------------------------------------
template <typename OutT>
__device__ __forceinline__ void gemm_body(const unsigned short* __restrict__ A,
                                          const unsigned short* __restrict__ BT,
                                          const float* __restrict__ bias,
                                          OutT* __restrict__ Cmat,
                                          int Ncols, int Kdim, int row0, int col0)
{
    __shared__ char As[128 * 128];
    __shared__ char Bs[128 * 128];

    const int tid = threadIdx.x, lane = tid & 63, w = tid >> 6;
    const int wr = w >> 1, wc = w & 1;
    const int slot = lane & 7, rsub = lane >> 3;

    f32x4 acc[4][4] = {};

    for (int k0 = 0; k0 < Kdim; k0 += 64) {
#pragma unroll
        for (int c = 0; c < 4; ++c) {
            const int chunk = c * 4 + w;
            const int r = chunk * 8 + rsub;
            gload16(As + chunk * 1024, A + (size_t)(row0 + r) * Kdim + k0 + 8 * (slot ^ (r & 7)));
            gload16(Bs + chunk * 1024, BT + (size_t)(col0 + r) * Kdim + k0 + 8 * (slot ^ (r & 7)));
        }
        __syncthreads();

#pragma unroll
        for (int kk = 0; kk < 2; ++kk) {
            const int kslot = kk * 4 + (lane >> 4);
            bf16x8 af[4], bf[4];
#pragma unroll
            for (int mi = 0; mi < 4; ++mi)
                af[mi] = *(const bf16x8*)(As + swz(wr * 64 + mi * 16 + (lane & 15), kslot));
#pragma unroll
            for (int ni = 0; ni < 4; ++ni)
                bf[ni] = *(const bf16x8*)(Bs + swz(wc * 64 + ni * 16 + (lane & 15), kslot));
            __builtin_amdgcn_s_setprio(1);
#pragma unroll
            for (int mi = 0; mi < 4; ++mi)
#pragma unroll
                for (int ni = 0; ni < 4; ++ni)
                    acc[mi][ni] = MFMA32(af[mi], bf[ni], acc[mi][ni]);
            __builtin_amdgcn_s_setprio(0);
        }
        __syncthreads();
    }

#pragma unroll
    for (int mi = 0; mi < 4; ++mi) {
        const int row = row0 + wr * 64 + mi * 16 + ((lane >> 4) << 2);
#pragma unroll
        for (int ni = 0; ni < 4; ++ni) {
            const int col = col0 + wc * 64 + ni * 16 + (lane & 15);
            const float bv_ = bias ? bias[col] : 0.f;
#pragma unroll
            for (int r = 0; r < 4; ++r) {
                const float v = acc[mi][ni][r] + bv_;
                if constexpr (sizeof(OutT) == 2)
                    Cmat[(size_t)(row + r) * Ncols + col] = (OutT)f2bf(v);
                else
                    Cmat[(size_t)(row + r) * Ncols + col] = v;
            }
        }
    }
}

// merged QKV projection: 1-D grid 1152, XCD-bijective decode so all 18
// (sel,colt) blocks sharing one A row-tile land on the same XCD's L2.
__global__ __launch_bounds__(256)
void gemm_qkv(const unsigned short* __restrict__ xb,
              const unsigned short* __restrict__ wqT, const unsigned short* __restrict__ wkT,
              const unsigned short* __restrict__ wvT, const float* __restrict__ bv,
              unsigned short* __restrict__ q_lin, unsigned short* __restrict__ k_lin,
              unsigned short* __restrict__ v_lin)
{
    const int id = blockIdx.x;
    const int j = id >> 3;
    const int bx = (id & 7) * 8 + j / 18;    // row-tile; 8 tiles per XCD
    const int by = j % 18;
    const int sel = by / 6, colt = by % 6;
    const unsigned short* BT; unsigned short* dst; const float* bias = nullptr;
    if (sel == 0)      { BT = wqT; dst = q_lin; }
    else if (sel == 1) { BT = wkT; dst = k_lin; }
    else               { BT = wvT; dst = v_lin; bias = bv; }
    gemm_body<unsigned short>(xb, BT, bias, dst, C_, C_, bx * 128, colt * 128);
}

// projection: 1-D grid 384, same XCD decode (6 col-tiles per row-tile)
__global__ __launch_bounds__(256)
void gemm_proj(const unsigned short* __restrict__ A, const unsigned short* __restrict__ BT,
               const float* __restrict__ bias, float* __restrict__ Cmat)
{
    const int id = blockIdx.x;
    const int j = id >> 3;
    const int bx = (id & 7) * 8 + j / 6;
    const int by = j % 6;
    gemm_body<float>(A, BT, bias, Cmat, C_, C_, bx * 128, by * 128);
}

// ---------------------------------------------------------------------------
// q/k depthwise causal conv over BATCH axis; bf16 in [B,N,C] -> bf16 [BH,N,64]
// w/bias loaded as float4 (contiguous [C][3] run per thread).
// ---------------------------------------------------------------------------
__global__ __launch_bounds__(256)
void dwconv_qk(const unsigned short* __restrict__ qlin, const unsigned short* __restrict__ klin,
               const float* __restrict__ cq_w, const float* __restrict__ cq_b,
               const float* __restrict__ ck_w, const float* __restrict__ ck_b,
               unsigned short* __restrict__ qc, unsigned short* __restrict__ kc)
{
    const unsigned short* lin; const float* w; const float* bias;
    unsigned short* out;
    if (blockIdx.y == 0) { lin = qlin; w = cq_w; bias = cq_b; out = qc; }
    else                 { lin = klin; w = ck_w; bias = ck_b; out = kc; }

    const int i = blockIdx.x * 256 + threadIdx.x;
    const int c8 = i % (C_ / 8);
    const int n  = (i / (C_ / 8)) % N_;
    const int b  = i / ((C_ / 8) * N_);
    const int c  = c8 * 8;

    float4 w4[6];
#pragma unroll
    for (int j4 = 0; j4 < 6; ++j4) w4[j4] = *(const float4*)(w + c * 3 + j4 * 4);
    const float* wf = (const float*)w4;          // wf[j*3+k], j=0..7
    float4 b4[2];
    b4[0] = *(const float4*)(bias + c);
    b4[1] = *(const float4*)(bias + c + 4);
    const float* bfv = (const float*)b4;

    const uint4 z4 = make_uint4(0, 0, 0, 0);
    const uint4 x0 = (b >= 2) ? *(const uint4*)(lin + ((size_t)(b - 2) * N_ + n) * C_ + c) : z4;
    const uint4 x1 = (b >= 1) ? *(const uint4*)(lin + ((size_t)(b - 1) * N_ + n) * C_ + c) : z4;
    const uint4 x2 = *(const uint4*)(lin + ((size_t)b * N_ + n) * C_ + c);
    const unsigned short* u0 = (const unsigned short*)&x0;
    const unsigned short* u1 = (const unsigned short*)&x1;
    const unsigned short* u2 = (const unsigned short*)&x2;

    unsigned short y[8];
#pragma unroll
    for (int j = 0; j < 8; ++j) {
        const float v = wf[j * 3 + 0] * bf2f(u0[j]) +
                        wf[j * 3 + 1] * bf2f(u1[j]) +
                        wf[j * 3 + 2] * bf2f(u2[j]) + bfv[j];
        y[j] = f2bf(v);
    }
    const int h = c8 >> 3, d0 = (c8 & 7) * 8;
    *(uint4*)(out + (((size_t)b * H_ + h) * N_ + n) * 64 + d0) = *(uint4*)y;
}

// ---------------------------------------------------------------------------
// v path: conv over batch + transpose, bf16 [B,N,C] -> vt [BH,64,N].
// Output rows with (d>>3)&1 store each 8-elem group with 4-elem halves
// SWAPPED -> attn's b64 V reads become LDS bank-conflict-free.
// ---------------------------------------------------------------------------
__global__ __launch_bounds__(256)
void conv_v_transpose(const unsigned short* __restrict__ vlin, const float* __restrict__ w,
                      const float* __restrict__ bias, unsigned short* __restrict__ vt)
{
    __shared__ unsigned short T[64][72];
    const int t = threadIdx.x;
    const int n0 = blockIdx.x * 64, bh = blockIdx.y;
    const int b = bh / H_, h = bh % H_;
    const int r = t >> 2, c0 = (t & 3) * 16;
    const int cbase = h * 64 + c0;

    float4 w4[12];
#pragma unroll
    for (int j4 = 0; j4 < 12; ++j4) w4[j4] = *(const float4*)(w + cbase * 3 + j4 * 4);
    const float* wf = (const float*)w4;          // wf[i*3+j], i=0..15
    float4 bb4[4];
#pragma unroll
    for (int j4 = 0; j4 < 4; ++j4) bb4[j4] = *(const float4*)(bias + cbase + j4 * 4);
    const float* bfv = (const float*)bb4;

    float acc[16];
#pragma unroll
    for (int i = 0; i < 16; ++i) acc[i] = bfv[i];
#pragma unroll
    for (int j = 0; j < 3; ++j) {
        const int bb = b - 2 + j;
        if (bb < 0) continue;
        const unsigned short* src = vlin + ((size_t)bb * N_ + n0 + r) * C_ + cbase;
        const uint4 va = *(const uint4*)src;
        const uint4 vb2 = *(const uint4*)(src + 8);
        const unsigned short* u = (const unsigned short*)&va;
        const unsigned short* u2 = (const unsigned short*)&vb2;
#pragma unroll
        for (int i = 0; i < 8; ++i)  acc[i]     += wf[i * 3 + j] * bf2f(u[i]);
#pragma unroll
        for (int i = 0; i < 8; ++i)  acc[8 + i] += wf[(8 + i) * 3 + j] * bf2f(u2[i]);
    }
    unsigned short tmp[16];
#pragma unroll
    for (int i = 0; i < 16; ++i) tmp[i] = f2bf(acc[i]);
    *(uint4*)&T[r][c0] = *(uint4*)tmp;
    *(uint4*)&T[r][c0 + 8] = *(uint4*)(tmp + 8);
    __syncthreads();

    const int d = t >> 2;
    const int sflip = ((d >> 3) & 1) << 2;       // swap 4-elem halves for odd d>>3
    unsigned short o[16];
#pragma unroll
    for (int e = 0; e < 8; ++e) o[e] = T[c0 + (e ^ sflip)][d];
#pragma unroll
    for (int e = 0; e < 8; ++e) o[8 + e] = T[c0 + 8 + (e ^ sflip)][d];
    uint4* dst = (uint4*)(vt + ((size_t)bh * 64 + d) * N_ + n0 + c0);
    dst[0] = *(uint4*)o; dst[1] = *(uint4*)(o + 8);
}

// ---------------------------------------------------------------------------
// Swapped-operand MFMA flash attention, QBLK=64 (4 waves x 16 q-rows).
// Q,K: [BH,N,64] bf16; Vt: [BH,64,N] bf16 (half-swapped rows); O: [B,N,C] bf16.
// S^T = mfma32(K, Q): lane (g,q) holds S[q][ni*16+4g+rg] -> in-lane softmax.
// PV via mfma_f32_16x16x16bf16_1k; V^T b64 reads conflict-free via the
// row-parity half-swap (byte bit3 = (g&1)^(q>>3&1)).
// Grid: 1536 blocks, XCD-bijective remap (head's K/V pinned to one L2).
// ---------------------------------------------------------------------------
__global__ __launch_bounds__(256)
void attn_mfma(const unsigned short* __restrict__ Qg, const unsigned short* __restrict__ Kg,
               const unsigned short* __restrict__ Vtg, unsigned short* __restrict__ Og)
{
    __shared__ char Kb[2][8192];
    __shared__ char Vb[2][8192];

    const int tid = threadIdx.x, lane = tid & 63, w = tid >> 6;
    const int g = lane >> 4, q = lane & 15;
    const int slot = lane & 7, rsub = lane >> 3;
    const int vsub = (((g & 1) ^ ((q >> 3) & 1)) << 3);   // V read half-select

    const int id = blockIdx.x;
    const int bh = (id & 7) * 12 + ((id >> 3) % 12);   // all 16 q-tiles of a head -> same XCD
    const int q0 = (id / 96) * 64;
    const int b = bh / H_, h = bh % H_;

    const unsigned short* Qp = Qg + (size_t)bh * N_ * 64;
    const unsigned short* Kp = Kg + (size_t)bh * N_ * 64;
    const unsigned short* Vp = Vtg + (size_t)bh * 64 * N_;

    // Q fragments straight to regs: lane holds Q[q0+w*16+q][kk*32+g*8..+8]
    bf16x8 qf[2];
#pragma unroll
    for (int kk = 0; kk < 2; ++kk)
        qf[kk] = *(const bf16x8*)(Qp + (size_t)(q0 + w * 16 + q) * 64 + kk * 32 + g * 8);

    // stage K,V tile 0
#pragma unroll
    for (int c = 0; c < 2; ++c) {
        const int chunk = c * 4 + w, r = chunk * 8 + rsub;
        gload16(Kb[0] + chunk * 1024, Kp + (size_t)r * 64 + 8 * (slot ^ (r & 7)));
        gload16(Vb[0] + chunk * 1024, Vp + (size_t)r * N_ + 8 * (slot ^ (r & 7)));
    }
    __syncthreads();

    f32x4 o[4] = {};
    float mrun = 0.f, lrun = 0.f;       // lrun is a PER-LANE partial
    const float cs = 0.18033688011112042f;   // 0.125 * log2(e)

    int buf = 0;
    for (int kt = 0; kt < N_ / 64; ++kt) {
        if (kt < N_ / 64 - 1) {
            const int nb = buf ^ 1;
#pragma unroll
            for (int c = 0; c < 2; ++c) {
                const int chunk = c * 4 + w, r = chunk * 8 + rsub;
                gload16(Kb[nb] + chunk * 1024, Kp + (size_t)((kt + 1) * 64 + r) * 64 + 8 * (slot ^ (r & 7)));
                gload16(Vb[nb] + chunk * 1024, Vp + (size_t)r * N_ + (kt + 1) * 64 + 8 * (slot ^ (r & 7)));
            }
        }

        // ---- S^T = K·Q^T: D rows = kv, cols = q ----
        f32x4 s[4] = {};
#pragma unroll
        for (int kk = 0; kk < 2; ++kk) {
            const int kslot = kk * 4 + g;
            bf16x8 kf[4];
#pragma unroll
            for (int ni = 0; ni < 4; ++ni)
                kf[ni] = *(const bf16x8*)(Kb[buf] + swz(ni * 16 + q, kslot));
            __builtin_amdgcn_s_setprio(1);
#pragma unroll
            for (int ni = 0; ni < 4; ++ni)
                s[ni] = MFMA32(kf[ni], qf[kk], s[ni]);
            __builtin_amdgcn_s_setprio(0);
        }

        // ---- in-lane softmax (base-2): raw max guard, fma-folded exp arg ----
        bf16x4 pf[4];
        {
            float m0 = s[0][0];
#pragma unroll
            for (int ni = 0; ni < 4; ++ni)
#pragma unroll
                for (int rg = 0; rg < 4; ++rg) m0 = fmaxf(m0, s[ni][rg]);
            m0 = fmaxf(m0, __shfl_xor(m0, 16));
            m0 = fmaxf(m0, __shfl_xor(m0, 32));
            if (__any(m0 * cs > mrun + 8.f)) {      // never fires for this data
                const float mnew = m0 * cs;
                const float f = exp2f(mrun - mnew);
                lrun *= f;
#pragma unroll
                for (int nd = 0; nd < 4; ++nd) o[nd] *= f;
                mrun = mnew;
            }
#pragma unroll
            for (int ni = 0; ni < 4; ++ni) {
                const float p0 = exp2f(fmaf(s[ni][0], cs, -mrun));
                const float p1 = exp2f(fmaf(s[ni][1], cs, -mrun));
                const float p2 = exp2f(fmaf(s[ni][2], cs, -mrun));
                const float p3 = exp2f(fmaf(s[ni][3], cs, -mrun));
                lrun += (p0 + p1) + (p2 + p3);
                bf16x4 pk;
                pk[0] = (bf16_t)p0; pk[1] = (bf16_t)p1; pk[2] = (bf16_t)p2; pk[3] = (bf16_t)p3;
                pf[ni] = pk;
            }
        }

        // ---- O^T += V^T·P^T (K=16 MFMA, operands lane-local) ----
#pragma unroll
        for (int ni = 0; ni < 4; ++ni) {
            bf16x4 vf[4];
#pragma unroll
            for (int nd = 0; nd < 4; ++nd) {
                const int d = nd * 16 + q;
                vf[nd] = *(const bf16x4*)(Vb[buf] + d * 128 +
                          ((((2 * ni + (g >> 1)) ^ (d & 7))) << 4) + vsub);
            }
            __builtin_amdgcn_s_setprio(1);
#pragma unroll
            for (int nd = 0; nd < 4; ++nd)
                o[nd] = MFMA16(vf[nd], pf[ni], o[nd]);
            __builtin_amdgcn_s_setprio(0);
        }

        __syncthreads();
        buf ^= 1;
    }

    // epilogue: reduce lrun across the q-group, then write O^T -> Og
    {
        lrun += __shfl_xor(lrun, 16);
        lrun += __shfl_xor(lrun, 32);
        const float inv = 1.0f / lrun;
        const int qrow = q0 + w * 16 + q;
        unsigned short* orow = Og + ((size_t)b * N_ + qrow) * C_ + h * D_;
#pragma unroll
        for (int nd = 0; nd < 4; ++nd) {
            unsigned short pk[4];
#pragma unroll
            for (int rg = 0; rg < 4; ++rg) pk[rg] = f2bf(o[nd][rg] * inv);
            *(uint2*)(orow + nd * 16 + 4 * g) = *(uint2*)pk;
        }
    }
}

// ---------------------------------------------------------------------------
extern "C" void kernel_launch(void* const* d_in, const int* in_sizes, int n_in,
                              void* d_out, int out_size, void* d_ws, size_t ws_size,
                              hipStream_t stream)
{
    (void)in_sizes; (void)n_in; (void)out_size; (void)ws_size;
    const float* x    = (const float*)d_in[0];
    const float* wq   = (const float*)d_in[1];
    const float* wk   = (const float*)d_in[2];
    const float* wv   = (const float*)d_in[3];
    const float* bv   = (const float*)d_in[4];
    const float* cq_w = (const float*)d_in[5];
    const float* cq_b = (const float*)d_in[6];
    const float* ck_w = (const float*)d_in[7];
    const float* ck_b = (const float*)d_in[8];
    const float* cv_w = (const float*)d_in[9];
    const float* cv_b = (const float*)d_in[10];
    const float* wo   = (const float*)d_in[11];
    const float* bo   = (const float*)d_in[12];
    float* out = (float*)d_out;

    char* wsb = (char*)d_ws;
    const size_t T  = (size_t)B_ * N_ * C_;       // 6,291,456 elems
    const size_t WB = (size_t)2 * 589824;         // one bf16 768x768
    unsigned short* xb  = (unsigned short*)wsb;                      // 2T B
    unsigned short* wqT = (unsigned short*)(wsb + 2 * T);
    unsigned short* wkT = wqT + 589824;
    unsigned short* wvT = wkT + 589824;
    unsigned short* woT = wvT + 589824;
    char* p = wsb + 2 * T + 4 * WB;
    unsigned short* q_lin = (unsigned short*)p;          p += 2 * T;
    unsigned short* k_lin = (unsigned short*)p;          p += 2 * T;
    unsigned short* v_lin = (unsigned short*)p;          p += 2 * T;
    unsigned short* qc    = (unsigned short*)p;          p += 2 * T;
    unsigned short* kc    = (unsigned short*)p;          p += 2 * T;
    unsigned short* vt    = (unsigned short*)p;          p += 2 * T;
    unsigned short* attn_out = xb;                 // xb dead after gemm_qkv

    const int M = B_ * N_;

    castx_kernel<<<dim3((int)(T / 8 / 256)), 256, 0, stream>>>(x, xb);
    castwT4_kernel<<<dim3(12, 12, 4), 256, 0, stream>>>(wq, wk, wv, wo, wqT, wkT, wvT, woT);

    gemm_qkv<<<dim3((M / 128) * 18), 256, 0, stream>>>(xb, wqT, wkT, wvT, bv, q_lin, k_lin, v_lin);

    dwconv_qk<<<dim3((int)(T / 8 / 256), 2), 256, 0, stream>>>(
        q_lin, k_lin, cq_w, cq_b, ck_w, ck_b, qc, kc);
    conv_v_transpose<<<dim3(N_ / 64, B_ * H_), 256, 0, stream>>>(v_lin, cv_w, cv_b, vt);

    attn_mfma<<<dim3(1536), 256, 0, stream>>>(qc, kc, vt, attn_out);

    gemm_proj<<<dim3((M / 128) * 6), 256, 0, stream>>>(attn_out, woT, bo, out);
}